// Round 1
// baseline (1002.572 us; speedup 1.0000x reference)
//
#include <hip/hip_runtime.h>
#include <hip/hip_bf16.h>
#include <math.h>

typedef unsigned short u16;
typedef u16 us8 __attribute__((ext_vector_type(8)));
typedef u16 us4 __attribute__((ext_vector_type(4)));
typedef float f32x4 __attribute__((ext_vector_type(4)));
typedef float f32x8 __attribute__((ext_vector_type(8)));
typedef __bf16 bf8 __attribute__((ext_vector_type(8)));

#define SCAN_B 256
#define CH 8192   // edges per bucket-sort block

__device__ __forceinline__ float bf2f(u16 v) {
    unsigned u = ((unsigned)v) << 16;
    return __builtin_bit_cast(float, u);
}
__device__ __forceinline__ u16 f2bf(float f) {
    unsigned u = __builtin_bit_cast(unsigned, f);
    unsigned lsb = (u >> 16) & 1;
    u += 0x7fff + lsb;
    return (u16)(u >> 16);
}
__device__ __forceinline__ void fma8(f32x8& acc, float w, us8 v) {
#pragma unroll
    for (int j = 0; j < 8; j++) acc[j] += w * bf2f(v[j]);
}

// ---------------- runtime dtype probes ----------------
__global__ void detect_k(const int* __restrict__ ei, int E,
                         const u16* __restrict__ xraw, int* flag) {
    __shared__ int c_i32, c_f32;
    if (threadIdx.x == 0) { c_i32 = 0; c_f32 = 0; }
    __syncthreads();
    int ne = (E < 4096) ? E : 4096;
    for (int e = threadIdx.x; e < ne; e += blockDim.x)
        if (ei[2 * e + 1] != 0) c_i32 = 1;
    for (int k = threadIdx.x; k < 8192; k += blockDim.x) {
        u16 v = xraw[2 * k];
        int ex = (v >> 7) & 0xFF;
        if (ex >= 0xF0) atomicAdd(&c_f32, 1);
    }
    __syncthreads();
    if (threadIdx.x == 0) {
        flag[0] = (c_i32 == 0) ? 1 : 0;
        flag[1] = (c_f32 >= 4) ? 1 : 0;
    }
}

// ---------------- canonicalize inputs (vectorized) ----------------
__global__ void cvt_x_k(const void* __restrict__ src, u16* __restrict__ dst,
                        long nq, const int* __restrict__ flag) {  // nq = n/4
    int f32m = flag[1];
    long i0 = (long)blockIdx.x * blockDim.x + threadIdx.x;
    long stride = (long)gridDim.x * blockDim.x;
    if (f32m) {
        const f32x4* s = (const f32x4*)src;
        for (long i = i0; i < nq; i += stride) {
            f32x4 v = s[i];
            us4 o;
            #pragma unroll
            for (int j = 0; j < 4; j++) o[j] = f2bf(v[j]);
            ((us4*)dst)[i] = o;
        }
    } else {
        const us4* s = (const us4*)src;
        for (long i = i0; i < nq; i += stride) ((us4*)dst)[i] = s[i];
    }
}

__global__ void cvt_wt_k(const void* __restrict__ W, u16* __restrict__ Wt,
                         int K, int Nn, const int* __restrict__ flag) {
    int t = blockIdx.x * blockDim.x + threadIdx.x;
    if (t >= K * Nn) return;
    int k = t / Nn, nn = t - k * Nn;
    u16 b;
    if (flag[1]) b = f2bf(((const float*)W)[t]);
    else         b = ((const u16*)W)[t];
    Wt[nn * K + k] = b;
}

struct PEnt { const void* s; int n; int off; };
struct PTab { PEnt e[14]; };
__global__ void cvt_params_k(PTab tab, float* __restrict__ pbuf,
                             const int* __restrict__ flag) {
    PEnt en = tab.e[blockIdx.x];
    int f32m = flag[1];
    for (int i = threadIdx.x; i < en.n; i += blockDim.x) {
        float v = f32m ? ((const float*)en.s)[i] : bf2f(((const u16*)en.s)[i]);
        pbuf[en.off + i] = v;
    }
}

// ---------------- CSR build (bucket-sorted, low write-amplification) ----------------
__global__ void init_counts_k(int* counts, int n) {
    int i = blockIdx.x * blockDim.x + threadIdx.x;
    if (i < n) counts[i] = 1;  // self-loop
}

// Pass A: per-block bucket histogram (bucket = dst >> shiftv)
__global__ void histA_k(const int* __restrict__ ei, const int* __restrict__ flag,
                        int* __restrict__ hist, int E, int n, int NB, int NBUK, int shiftv) {
    __shared__ int lh[256];
    int blk = blockIdx.x;
    for (int b = threadIdx.x; b < NBUK; b += 256) lh[b] = 0;
    __syncthreads();
    int e0 = blk * CH;
    int e1 = min(e0 + CH, E);
    int i64 = flag[0];
    for (int e = e0 + threadIdx.x; e < e1; e += 256) {
        int d;
        if (i64) d = (int)((const long long*)ei)[(size_t)E + e];
        else     d = ei[(size_t)E + e];
        int b = ((unsigned)d < (unsigned)n) ? min(d >> shiftv, NBUK - 1) : (NBUK - 1);
        atomicAdd(&lh[b], 1);
    }
    __syncthreads();
    for (int b = threadIdx.x; b < NBUK; b += 256) hist[b * NB + blk] = lh[b];
}

// generic block-scan (also reused for node-degree scan)
__global__ void scan1_k(const int* __restrict__ counts, int* incl, int* bsum, int n) {
    __shared__ int tmp[SCAN_B];
    int t = threadIdx.x;
    int i = blockIdx.x * SCAN_B + t;
    int v = (i < n) ? counts[i] : 0;
    tmp[t] = v;
    __syncthreads();
    for (int o = 1; o < SCAN_B; o <<= 1) {
        int x = 0;
        if (t >= o) x = tmp[t - o];
        __syncthreads();
        if (t >= o) tmp[t] += x;
        __syncthreads();
    }
    if (i < n) incl[i] = tmp[t];
    if (t == SCAN_B - 1) bsum[blockIdx.x] = tmp[t];
}

__global__ void scan2_k(const int* __restrict__ bsum, int* bscan, int nb) {
    __shared__ int tmp[SCAN_B];
    int t = threadIdx.x;
    tmp[t] = (t < nb) ? bsum[t] : 0;
    __syncthreads();
    for (int o = 1; o < SCAN_B; o <<= 1) {
        int x = 0;
        if (t >= o) x = tmp[t - o];
        __syncthreads();
        if (t >= o) tmp[t] += x;
        __syncthreads();
    }
    bscan[t] = tmp[t];
}

// Pass B epilogue: exclusive offsets ofs[i] = inclusive[i] + blockoff - hist[i]
__global__ void exclA_k(const int* __restrict__ incl, const int* __restrict__ bscan,
                        const int* __restrict__ hist, int* __restrict__ ofs, int len) {
    int i = blockIdx.x * 256 + threadIdx.x;
    if (i < len) {
        int boff = (blockIdx.x > 0) ? bscan[blockIdx.x - 1] : 0;
        ofs[i] = incl[i] + boff - hist[i];
    }
}

// Pass C: bucket-scatter packed (src,dst) pairs via LDS cursors
__global__ void scatC_k(const int* __restrict__ ei, const int* __restrict__ flag,
                        const int* __restrict__ ofs, long long* __restrict__ ebuf,
                        int E, int n, int NB, int NBUK, int shiftv) {
    __shared__ int cur[256];
    int blk = blockIdx.x;
    for (int b = threadIdx.x; b < NBUK; b += 256) cur[b] = ofs[b * NB + blk];
    __syncthreads();
    int e0 = blk * CH;
    int e1 = min(e0 + CH, E);
    int i64 = flag[0];
    for (int e = e0 + threadIdx.x; e < e1; e += 256) {
        int s, d;
        if (i64) {
            const long long* e64 = (const long long*)ei;
            s = (int)e64[e]; d = (int)e64[(size_t)E + e];
        } else {
            s = ei[e]; d = ei[(size_t)E + e];
        }
        int b = ((unsigned)d < (unsigned)n) ? min(d >> shiftv, NBUK - 1) : (NBUK - 1);
        int pos = atomicAdd(&cur[b], 1);
        ebuf[pos] = ((long long)(unsigned)d << 32) | (unsigned)s;
    }
}

// degree count on bucket-sorted pairs (L2-hot counters)
__global__ void count_ebuf_k(const long long* __restrict__ ebuf, int* counts, int E, int n) {
    int e = blockIdx.x * blockDim.x + threadIdx.x;
    if (e >= E) return;
    long long pr = ebuf[e];
    int d = (int)(pr >> 32);
    if ((unsigned)d < (unsigned)n) atomicAdd(&counts[d], 1);
}

__global__ void dinv_k(const int* __restrict__ counts, float* dinv, int n) {
    int i = blockIdx.x * blockDim.x + threadIdx.x;
    if (i < n) dinv[i] = rsqrtf((float)counts[i]);
}

__global__ void rowptr_k(const int* __restrict__ incl, const int* __restrict__ bscan,
                         int* rowptr, int n) {
    int i = blockIdx.x * blockDim.x + threadIdx.x;
    if (i < n) {
        int boff = (blockIdx.x > 0) ? bscan[blockIdx.x - 1] : 0;
        rowptr[i + 1] = incl[i] + boff;
        if (i == 0) rowptr[0] = 0;
    }
}

__global__ void cursor_k(const int* __restrict__ rowptr, int* cursor, int n) {
    int i = blockIdx.x * blockDim.x + threadIdx.x;
    if (i < n) cursor[i] = rowptr[i];
}

// Pass D: final CSR scatter from bucket-sorted pairs (dense col-window writes)
__global__ void scatD_k(const long long* __restrict__ ebuf, int* cursor,
                        int* __restrict__ col, int E, int n) {
    int e = blockIdx.x * blockDim.x + threadIdx.x;
    if (e < E) {
        long long pr = ebuf[e];
        int d = (int)(pr >> 32);
        int s = (int)(pr & 0xffffffffLL);
        if ((unsigned)s < (unsigned)n && (unsigned)d < (unsigned)n) {
            int pos = atomicAdd(&cursor[d], 1);
            col[pos] = s;
        }
    } else if (e < E + n) {
        int i = e - E;
        int pos = atomicAdd(&cursor[i], 1);
        col[pos] = i;
    }
}

// ---------------- bf16 MFMA GEMM (m97 structure): C[M,Nn] = A[M,K] * Bt[Nn,K]^T -------
// 128x128 tile, BK=32, 4 waves x (4x4 16x16 fragments), global_load_lds width-16.
typedef __attribute__((address_space(1))) const void gas_v;
typedef __attribute__((address_space(3))) void las_v;

__global__ __launch_bounds__(256) void gemm128_k(
    const u16* __restrict__ A, const u16* __restrict__ Bt,
    u16* __restrict__ C, int M, int K, int Nn) {
    __shared__ u16 As[128 * 32];
    __shared__ u16 Bs[128 * 32];
    int tid = threadIdx.x;
    int wave = tid >> 6;
    int lane = tid & 63;
    int wr = (wave >> 1) * 64;   // wave row offset in tile
    int wc = (wave & 1) * 64;    // wave col offset in tile
    long row0 = (long)blockIdx.x * 128;
    int col0 = blockIdx.y * 128;
    int lr = lane >> 2;          // 0..15 : row within 16-row staging chunk
    int lc = lane & 3;           // 0..3  : 16B column chunk
    int m = lane & 15;
    int q = lane >> 4;

    f32x4 acc[4][4];
    #pragma unroll
    for (int i = 0; i < 4; i++)
        #pragma unroll
        for (int j = 0; j < 4; j++) acc[i][j] = (f32x4){0.f, 0.f, 0.f, 0.f};

    for (int k0 = 0; k0 < K; k0 += 32) {
        // stage A,B tiles: 8 chunks of 16 rows each; wave w handles chunks w and w+4.
        // LDS is linear [128][32] bf16 (64B/row): chunk c occupies bytes
        // [c*1024, c*1024+1024), lane l writes base + l*16 == row-major position. [m97]
        #pragma unroll
        for (int p = 0; p < 2; p++) {
            int c = wave + p * 4;
            long ar = row0 + c * 16 + lr;
            if (ar > (long)M - 1) ar = (long)M - 1;  // clamp: garbage feeds masked rows only
            const u16* ga = A + ar * K + k0 + lc * 8;
            __builtin_amdgcn_global_load_lds((gas_v*)ga, (las_v*)&As[c * 512], 16, 0, 0);
            int br = col0 + c * 16 + lr;             // Nn % 128 == 0, always in-bounds
            const u16* gb = Bt + (size_t)br * K + k0 + lc * 8;
            __builtin_amdgcn_global_load_lds((gas_v*)gb, (las_v*)&Bs[c * 512], 16, 0, 0);
        }
        __syncthreads();   // compiler drains vmcnt before s_barrier

        us8 av[4], bv[4];
        #pragma unroll
        for (int i = 0; i < 4; i++) {
            av[i] = *(const us8*)&As[(wr + i * 16 + m) * 32 + q * 8];
            bv[i] = *(const us8*)&Bs[(wc + i * 16 + m) * 32 + q * 8];
        }
        #pragma unroll
        for (int i = 0; i < 4; i++) {
            bf8 fa = __builtin_bit_cast(bf8, av[i]);
            #pragma unroll
            for (int j = 0; j < 4; j++) {
                bf8 fb = __builtin_bit_cast(bf8, bv[j]);
                acc[i][j] = __builtin_amdgcn_mfma_f32_16x16x32_bf16(fa, fb, acc[i][j], 0, 0, 0);
            }
        }
        __syncthreads();
    }

    // C/D layout: col = lane&15, row = (lane>>4)*4 + r  [measured m89]
    #pragma unroll
    for (int i = 0; i < 4; i++) {
        #pragma unroll
        for (int r = 0; r < 4; r++) {
            long row = row0 + wr + i * 16 + q * 4 + r;
            if (row < M) {
                #pragma unroll
                for (int j = 0; j < 4; j++)
                    C[row * Nn + col0 + wc + j * 16 + m] = f2bf(acc[i][j][r]);
            }
        }
    }
}

// ---------------- wave-per-node aggregate [+ bias + LN + ELU (+resid) (+classifier)] ---
__global__ __launch_bounds__(256) void agg_k(
    const u16* __restrict__ in, const int* __restrict__ rowptr,
    const int* __restrict__ col, const float* __restrict__ dinv,
    const float* __restrict__ bias, const float* __restrict__ gamma,
    const float* __restrict__ beta, u16* __restrict__ out_h,
    const u16* __restrict__ resid, void* __restrict__ final_base,
    const int* __restrict__ flag, const float* __restrict__ Wcf,
    const float* __restrict__ bcf, int F, int nN) {
    int wv = threadIdx.x >> 6;
    int lane = threadIdx.x & 63;
    int i = blockIdx.x * 4 + wv;
    if (i >= nN) return;

    int rowt = F >> 3;                    // 32 (F=256) or 16 (F=128)
    int Gw = 64 / rowt;                   // 2 or 4 edge groups per wave
    int g = lane / rowt;
    int f0 = (lane & (rowt - 1)) << 3;

    int beg = rowptr[i], end = rowptr[i + 1];
    // unroll-4: 4 independent gathers in flight per wave (latency hiding, MLP)
    f32x8 acc = {0, 0, 0, 0, 0, 0, 0, 0}, acc2 = acc, acc3 = acc, acc4 = acc;
    int e = beg + g;
    for (; e + 3 * Gw < end; e += 4 * Gw) {
        int s0 = col[e], s1 = col[e + Gw], s2 = col[e + 2 * Gw], s3 = col[e + 3 * Gw];
        s0 = ((unsigned)s0 < (unsigned)nN) ? s0 : 0;
        s1 = ((unsigned)s1 < (unsigned)nN) ? s1 : 0;
        s2 = ((unsigned)s2 < (unsigned)nN) ? s2 : 0;
        s3 = ((unsigned)s3 < (unsigned)nN) ? s3 : 0;
        float w0 = dinv[s0], w1 = dinv[s1], w2 = dinv[s2], w3 = dinv[s3];
        us8 v0 = *(const us8*)(in + (unsigned)(s0 * F) + f0);
        us8 v1 = *(const us8*)(in + (unsigned)(s1 * F) + f0);
        us8 v2 = *(const us8*)(in + (unsigned)(s2 * F) + f0);
        us8 v3 = *(const us8*)(in + (unsigned)(s3 * F) + f0);
        fma8(acc, w0, v0);
        fma8(acc2, w1, v1);
        fma8(acc3, w2, v2);
        fma8(acc4, w3, v3);
    }
    for (; e + Gw < end; e += 2 * Gw) {
        int s0 = col[e], s1 = col[e + Gw];
        s0 = ((unsigned)s0 < (unsigned)nN) ? s0 : 0;
        s1 = ((unsigned)s1 < (unsigned)nN) ? s1 : 0;
        float w0 = dinv[s0], w1 = dinv[s1];
        us8 v0 = *(const us8*)(in + (unsigned)(s0 * F) + f0);
        us8 v1 = *(const us8*)(in + (unsigned)(s1 * F) + f0);
        fma8(acc, w0, v0);
        fma8(acc2, w1, v1);
    }
    if (e < end) {
        int s = col[e];
        s = ((unsigned)s < (unsigned)nN) ? s : 0;
        us8 v = *(const us8*)(in + (unsigned)(s * F) + f0);
        fma8(acc, dinv[s], v);
    }
    #pragma unroll
    for (int j = 0; j < 8; j++) acc[j] = (acc[j] + acc2[j]) + (acc3[j] + acc4[j]);

    for (int o = 32; o >= rowt; o >>= 1) {
        #pragma unroll
        for (int j = 0; j < 8; j++) acc[j] += __shfl_down(acc[j], o);
    }
    bool active = lane < rowt;
    float di = dinv[i];

    if (!bias) {  // plain mode (layer-2 pre-aggregate)
        if (active) {
            us8 o8;
            #pragma unroll
            for (int j = 0; j < 8; j++) o8[j] = f2bf(di * acc[j]);
            *(us8*)(out_h + (unsigned)(i * F) + f0) = o8;
        }
        return;
    }

    f32x8 accv = {0, 0, 0, 0, 0, 0, 0, 0};
    if (active) {
        #pragma unroll
        for (int j = 0; j < 8; j++) accv[j] = di * acc[j] + bias[f0 + j];
    }
    int f32m = final_base ? flag[1] : 0;
    if (final_base && active) {
        size_t conv_idx = (size_t)nN * 4 + (size_t)i * F + f0;
        if (f32m) {
            #pragma unroll
            for (int j = 0; j < 8; j++) ((float*)final_base)[conv_idx + j] = accv[j];
        } else {
            us8 o8;
            #pragma unroll
            for (int j = 0; j < 8; j++) o8[j] = f2bf(accv[j]);
            *(us8*)((u16*)final_base + conv_idx) = o8;
        }
    }

    float p1 = 0.f, p2 = 0.f;
    #pragma unroll
    for (int j = 0; j < 8; j++) { p1 += accv[j]; p2 += accv[j] * accv[j]; }
    for (int o = rowt >> 1; o >= 1; o >>= 1) {
        p1 += __shfl_xor(p1, o);
        p2 += __shfl_xor(p2, o);
    }
    float invF = 1.0f / (float)F;
    float mu = p1 * invF;
    float var = fmaxf(p2 * invF - mu * mu, 0.f);
    float rstd = rsqrtf(var + 1e-5f);

    f32x8 h8 = {0, 0, 0, 0, 0, 0, 0, 0};
    if (active) {
        f32x8 y8;
        #pragma unroll
        for (int j = 0; j < 8; j++)
            y8[j] = (accv[j] - mu) * rstd * gamma[f0 + j] + beta[f0 + j];
        if (final_base) {
            size_t bn_idx = (size_t)nN * 4 + (size_t)nN * F + (size_t)i * F + f0;
            if (f32m) {
                #pragma unroll
                for (int j = 0; j < 8; j++) ((float*)final_base)[bn_idx + j] = y8[j];
            } else {
                us8 o8;
                #pragma unroll
                for (int j = 0; j < 8; j++) o8[j] = f2bf(y8[j]);
                *(us8*)((u16*)final_base + bn_idx) = o8;
            }
        }
        #pragma unroll
        for (int j = 0; j < 8; j++) h8[j] = (y8[j] > 0.f) ? y8[j] : expm1f(y8[j]);
        if (resid) {
            us8 r8 = *(const us8*)(resid + (unsigned)(i * F) + f0);
            #pragma unroll
            for (int j = 0; j < 8; j++) h8[j] += bf2f(r8[j]);
        }
        if (out_h) {
            us8 o8;
            #pragma unroll
            for (int j = 0; j < 8; j++) o8[j] = f2bf(h8[j]);
            *(us8*)(out_h + (unsigned)(i * F) + f0) = o8;
        }
    }

    if (Wcf) {
        float s0 = 0.f, s1 = 0.f, s2 = 0.f, s3 = 0.f;
        if (active) {
            #pragma unroll
            for (int j = 0; j < 8; j++) {
                const float* wr = Wcf + (f0 + j) * 4;
                s0 += h8[j] * wr[0];
                s1 += h8[j] * wr[1];
                s2 += h8[j] * wr[2];
                s3 += h8[j] * wr[3];
            }
        }
        for (int o = rowt >> 1; o >= 1; o >>= 1) {
            s0 += __shfl_xor(s0, o);
            s1 += __shfl_xor(s1, o);
            s2 += __shfl_xor(s2, o);
            s3 += __shfl_xor(s3, o);
        }
        if (lane == 0) {
            size_t lidx = (size_t)i * 4;
            if (f32m) {
                ((float*)final_base)[lidx + 0] = s0 + bcf[0];
                ((float*)final_base)[lidx + 1] = s1 + bcf[1];
                ((float*)final_base)[lidx + 2] = s2 + bcf[2];
                ((float*)final_base)[lidx + 3] = s3 + bcf[3];
            } else {
                ((u16*)final_base)[lidx + 0] = f2bf(s0 + bcf[0]);
                ((u16*)final_base)[lidx + 1] = f2bf(s1 + bcf[1]);
                ((u16*)final_base)[lidx + 2] = f2bf(s2 + bcf[2]);
                ((u16*)final_base)[lidx + 3] = f2bf(s3 + bcf[3]);
            }
        }
    }
}

// ---------------- bias + LayerNorm + ELU in place, wave-per-node, F=512 ----------
__global__ __launch_bounds__(256) void ln_elu_k(u16* __restrict__ h,
                                                const float* __restrict__ bias,
                                                const float* __restrict__ gamma,
                                                const float* __restrict__ beta, int nN) {
    int wv = threadIdx.x >> 6;
    int lane = threadIdx.x & 63;
    int i = blockIdx.x * 4 + wv;
    if (i >= nN) return;
    int f0 = lane * 8;                       // 64 lanes x 8 = 512 features
    size_t base = (size_t)i * 512 + f0;
    us8 v8 = *(const us8*)(h + base);
    f32x8 v;
    #pragma unroll
    for (int j = 0; j < 8; j++) v[j] = bf2f(v8[j]) + bias[f0 + j];
    float p1 = 0.f, p2 = 0.f;
    #pragma unroll
    for (int j = 0; j < 8; j++) { p1 += v[j]; p2 += v[j] * v[j]; }
    #pragma unroll
    for (int o = 32; o >= 1; o >>= 1) {
        p1 += __shfl_xor(p1, o);
        p2 += __shfl_xor(p2, o);
    }
    const float invF = 1.0f / 512.0f;
    float mu = p1 * invF;
    float var = fmaxf(p2 * invF - mu * mu, 0.f);
    float rstd = rsqrtf(var + 1e-5f);
    us8 o8;
    #pragma unroll
    for (int j = 0; j < 8; j++) {
        float y = (v[j] - mu) * rstd * gamma[f0 + j] + beta[f0 + j];
        y = (y > 0.f) ? y : expm1f(y);
        o8[j] = f2bf(y);
    }
    *(us8*)(h + base) = o8;
}

// ---------------- ws-too-small marker ----------------
__global__ void marker_k(float* out) {
    if (threadIdx.x == 0 && blockIdx.x == 0) {
        out[0] = 31337.0f; out[1] = 31337.0f;
    }
}

extern "C" void kernel_launch(void* const* d_in, const int* in_sizes, int n_in,
                              void* d_out, int out_size, void* d_ws, size_t ws_size,
                              hipStream_t stream) {
    const int N = in_sizes[0] / 512;   // 50000
    const int E = in_sizes[1] / 2;     // 1600000

    const void* x  = d_in[0];
    const int* ei  = (const int*)d_in[1];

    // ---- workspace carve ----
    char* p = (char*)d_ws;
    auto alloc = [&](size_t bytes) -> void* {
        void* r = (void*)p;
        p += (bytes + 255) & ~(size_t)255;
        return r;
    };
    int*   flag   = (int*)alloc(256);
    int*   counts = (int*)alloc((size_t)N * 4);
    int*   rowptr = (int*)alloc((size_t)(N + 1) * 4);
    int*   cursor = (int*)alloc((size_t)N * 4);
    int*   incl   = (int*)alloc((size_t)N * 4);
    int*   bsum   = (int*)alloc(256 * 4);
    int*   bscan  = (int*)alloc(256 * 4);
    float* dinv   = (float*)alloc((size_t)N * 4);
    int*   col    = (int*)alloc((size_t)(E + N) * 4);
    float* pbuf   = (float*)alloc(4096 * 4);
    u16* W1t = (u16*)alloc((size_t)512 * 256 * 2);
    u16* W2t = (u16*)alloc((size_t)256 * 512 * 2);
    u16* W3t = (u16*)alloc((size_t)512 * 256 * 2);
    u16* W4t = (u16*)alloc((size_t)256 * 128 * 2);
    u16* bigA = (u16*)alloc((size_t)N * 512 * 2);  // xbf -> h2
    u16* xw   = (u16*)alloc((size_t)N * 256 * 2);  // ebuf (CSR build) -> GEMM scratch
    u16* h1   = (u16*)alloc((size_t)N * 256 * 2);  // hist arrays (CSR build) -> h1

    size_t needed = (size_t)(p - (char*)d_ws);
    if (needed > ws_size) {
        marker_k<<<1, 64, 0, stream>>>((float*)d_out);
        return;
    }

    u16* xbf = bigA;
    u16* h2  = bigA;  // [N,512], alive after xbf dead

    // bucket-sort params (dead buffers aliased; all CSR work precedes their next use)
    int shiftv = 8;
    while (((N - 1) >> shiftv) > 255) shiftv++;
    int NBUK = ((N - 1) >> shiftv) + 1;            // 196 for N=50000
    int NB_E = (E + CH - 1) / CH;                  // 196 for E=1.6M
    int flatlen = NBUK * NB_E;                     // ~38k
    int NH = (flatlen + 255) / 256;                // <=256 required
    long long* ebuf = (long long*)xw;              // E*8 B <= N*256*2 B
    int* hist     = (int*)h1;
    int* histincl = hist + flatlen;
    int* ofs      = histincl + flatlen;

    PTab tab;
    tab.e[0]  = { d_in[3],  256, 0    };  // b1
    tab.e[1]  = { d_in[12], 256, 256  };  // g1
    tab.e[2]  = { d_in[13], 256, 512  };  // be1
    tab.e[3]  = { d_in[5],  512, 768  };  // b2
    tab.e[4]  = { d_in[14], 512, 1280 };  // g2
    tab.e[5]  = { d_in[15], 512, 1792 };  // be2
    tab.e[6]  = { d_in[7],  256, 2304 };  // b3
    tab.e[7]  = { d_in[16], 256, 2560 };  // g3
    tab.e[8]  = { d_in[17], 256, 2816 };  // be3
    tab.e[9]  = { d_in[9],  128, 3072 };  // b4
    tab.e[10] = { d_in[18], 128, 3200 };  // g4
    tab.e[11] = { d_in[19], 128, 3328 };  // be4
    tab.e[12] = { d_in[10], 512, 3456 };  // Wc
    tab.e[13] = { d_in[11], 4,   3968 };  // bc
    float* b1f = pbuf + 0,   *g1f = pbuf + 256,  *be1f = pbuf + 512;
    float* b2f = pbuf + 768, *g2f = pbuf + 1280, *be2f = pbuf + 1792;
    float* b3f = pbuf + 2304,*g3f = pbuf + 2560, *be3f = pbuf + 2816;
    float* b4f = pbuf + 3072,*g4f = pbuf + 3200, *be4f = pbuf + 3328;
    float* Wcf = pbuf + 3456,*bcf = pbuf + 3968;

    int nb1 = (N + 255) / 256;
    int NB = (N + SCAN_B - 1) / SCAN_B;

    // ---- dtype probes ----
    detect_k<<<1, 256, 0, stream>>>(ei, E, (const u16*)x, flag);

    // ---- canonicalize ----
    cvt_x_k<<<4096, 256, 0, stream>>>(x, xbf, (long)N * 512 / 4, flag);
    cvt_wt_k<<<(512 * 256 + 255) / 256, 256, 0, stream>>>(d_in[2], W1t, 512, 256, flag);
    cvt_wt_k<<<(256 * 512 + 255) / 256, 256, 0, stream>>>(d_in[4], W2t, 256, 512, flag);
    cvt_wt_k<<<(512 * 256 + 255) / 256, 256, 0, stream>>>(d_in[6], W3t, 512, 256, flag);
    cvt_wt_k<<<(256 * 128 + 255) / 256, 256, 0, stream>>>(d_in[8], W4t, 256, 128, flag);
    cvt_params_k<<<14, 256, 0, stream>>>(tab, pbuf, flag);

    // ---- CSR build (bucket-sorted) ----
    histA_k<<<NB_E, 256, 0, stream>>>(ei, flag, hist, E, N, NB_E, NBUK, shiftv);
    scan1_k<<<NH, SCAN_B, 0, stream>>>(hist, histincl, bsum, flatlen);
    scan2_k<<<1, SCAN_B, 0, stream>>>(bsum, bscan, NH);
    exclA_k<<<NH, 256, 0, stream>>>(histincl, bscan, hist, ofs, flatlen);
    scatC_k<<<NB_E, 256, 0, stream>>>(ei, flag, ofs, ebuf, E, N, NB_E, NBUK, shiftv);
    init_counts_k<<<nb1, 256, 0, stream>>>(counts, N);
    count_ebuf_k<<<(E + 255) / 256, 256, 0, stream>>>(ebuf, counts, E, N);
    dinv_k<<<nb1, 256, 0, stream>>>(counts, dinv, N);
    scan1_k<<<NB, SCAN_B, 0, stream>>>(counts, incl, bsum, N);
    scan2_k<<<1, SCAN_B, 0, stream>>>(bsum, bscan, NB);
    rowptr_k<<<NB, SCAN_B, 0, stream>>>(incl, bscan, rowptr, N);
    cursor_k<<<nb1, 256, 0, stream>>>(rowptr, cursor, N);
    scatD_k<<<(E + N + 255) / 256, 256, 0, stream>>>(ebuf, cursor, col, E, N);

    int gx = (N + 127) / 128;          // 391
    int ga = (N + 3) / 4;

    // ---- layer 1: xbf[N,512] @ W1 -> agg+LN+ELU -> h1[N,256] ----
    gemm128_k<<<dim3(gx, 256 / 128), 256, 0, stream>>>(xbf, W1t, xw, N, 512, 256);
    agg_k<<<ga, 256, 0, stream>>>(xw, rowptr, col, dinv, b1f, g1f, be1f,
                                  h1, nullptr, nullptr, flag, nullptr, nullptr, 256, N);
    // ---- layer 2 (agg BEFORE GEMM: agg(h1 @ W2) == agg(h1) @ W2) ----
    agg_k<<<ga, 256, 0, stream>>>(h1, rowptr, col, dinv, nullptr, nullptr, nullptr,
                                  xw, nullptr, nullptr, flag, nullptr, nullptr, 256, N);
    gemm128_k<<<dim3(gx, 512 / 128), 256, 0, stream>>>(xw, W2t, h2, N, 256, 512);
    ln_elu_k<<<ga, 256, 0, stream>>>(h2, b2f, g2f, be2f, N);
    // ---- layer 3: h2[N,512] @ W3 -> agg+LN+ELU + h1 -> h1[N,256] ----
    gemm128_k<<<dim3(gx, 256 / 128), 256, 0, stream>>>(h2, W3t, xw, N, 512, 256);
    agg_k<<<ga, 256, 0, stream>>>(xw, rowptr, col, dinv, b3f, g3f, be3f,
                                  h1, h1, nullptr, flag, nullptr, nullptr, 256, N);
    // ---- layer 4: h1[N,256] @ W4 -> agg -> out_conv/out_bn + fused classifier ----
    gemm128_k<<<dim3(gx, 128 / 128), 256, 0, stream>>>(h1, W4t, xw, N, 256, 128);
    agg_k<<<ga, 256, 0, stream>>>(xw, rowptr, col, dinv, b4f, g4f, be4f,
                                  nullptr, nullptr, d_out, flag, Wcf, bcf, 128, N);
}

// Round 3
// 984.261 us; speedup vs baseline: 1.0186x; 1.0186x over previous
//
#include <hip/hip_runtime.h>
#include <hip/hip_bf16.h>
#include <math.h>

typedef unsigned short u16;
typedef u16 us8 __attribute__((ext_vector_type(8)));
typedef u16 us4 __attribute__((ext_vector_type(4)));
typedef float f32x4 __attribute__((ext_vector_type(4)));
typedef float f32x8 __attribute__((ext_vector_type(8)));
typedef __bf16 bf8 __attribute__((ext_vector_type(8)));

#define SCAN_B 256
#define CH 8192   // edges per bucket-sort block

__device__ __forceinline__ float bf2f(u16 v) {
    unsigned u = ((unsigned)v) << 16;
    return __builtin_bit_cast(float, u);
}
__device__ __forceinline__ u16 f2bf(float f) {
    unsigned u = __builtin_bit_cast(unsigned, f);
    unsigned lsb = (u >> 16) & 1;
    u += 0x7fff + lsb;
    return (u16)(u >> 16);
}
__device__ __forceinline__ void fma8(f32x8& acc, float w, us8 v) {
#pragma unroll
    for (int j = 0; j < 8; j++) acc[j] += w * bf2f(v[j]);
}

// ---------------- runtime dtype probes ----------------
__global__ void detect_k(const int* __restrict__ ei, int E,
                         const u16* __restrict__ xraw, int* flag) {
    __shared__ int c_i32, c_f32;
    if (threadIdx.x == 0) { c_i32 = 0; c_f32 = 0; }
    __syncthreads();
    int ne = (E < 4096) ? E : 4096;
    for (int e = threadIdx.x; e < ne; e += blockDim.x)
        if (ei[2 * e + 1] != 0) c_i32 = 1;
    for (int k = threadIdx.x; k < 8192; k += blockDim.x) {
        u16 v = xraw[2 * k];
        int ex = (v >> 7) & 0xFF;
        if (ex >= 0xF0) atomicAdd(&c_f32, 1);
    }
    __syncthreads();
    if (threadIdx.x == 0) {
        flag[0] = (c_i32 == 0) ? 1 : 0;
        flag[1] = (c_f32 >= 4) ? 1 : 0;
    }
}

// ---------------- canonicalize inputs (vectorized) ----------------
__global__ void cvt_x_k(const void* __restrict__ src, u16* __restrict__ dst,
                        long nq, const int* __restrict__ flag) {  // nq = n/4
    int f32m = flag[1];
    long i0 = (long)blockIdx.x * blockDim.x + threadIdx.x;
    long stride = (long)gridDim.x * blockDim.x;
    if (f32m) {
        const f32x4* s = (const f32x4*)src;
        for (long i = i0; i < nq; i += stride) {
            f32x4 v = s[i];
            us4 o;
            #pragma unroll
            for (int j = 0; j < 4; j++) o[j] = f2bf(v[j]);
            ((us4*)dst)[i] = o;
        }
    } else {
        const us4* s = (const us4*)src;
        for (long i = i0; i < nq; i += stride) ((us4*)dst)[i] = s[i];
    }
}

// merged 4-matrix transpose+convert: W[K][Nn] -> Wt[Nn][K]
struct WEnt { const void* s; u16* dst; int K; int Nn; int base; };
__global__ void cvt_wts_k(WEnt e0, WEnt e1, WEnt e2, WEnt e3,
                          const int* __restrict__ flag, int total) {
    int t = blockIdx.x * blockDim.x + threadIdx.x;
    if (t >= total) return;
    WEnt en = (t >= e3.base) ? e3 : ((t >= e2.base) ? e2 : ((t >= e1.base) ? e1 : e0));
    int li = t - en.base;
    int k = li / en.Nn, nn = li - k * en.Nn;
    u16 b;
    if (flag[1]) b = f2bf(((const float*)en.s)[li]);
    else         b = ((const u16*)en.s)[li];
    en.dst[nn * en.K + k] = b;
}

struct PEnt { const void* s; int n; int off; };
struct PTab { PEnt e[14]; };
__global__ void cvt_params_k(PTab tab, float* __restrict__ pbuf,
                             const int* __restrict__ flag) {
    PEnt en = tab.e[blockIdx.x];
    int f32m = flag[1];
    for (int i = threadIdx.x; i < en.n; i += blockDim.x) {
        float v = f32m ? ((const float*)en.s)[i] : bf2f(((const u16*)en.s)[i]);
        pbuf[en.off + i] = v;
    }
}

// ---------------- CSR build (bucket-sorted, low write-amplification) ----------------
__global__ void init_counts_k(int* counts, int n) {
    int i = blockIdx.x * blockDim.x + threadIdx.x;
    if (i < n) counts[i] = 1;  // self-loop
}

// Pass A: per-block bucket histogram (bucket = dst >> shiftv)
__global__ void histA_k(const int* __restrict__ ei, const int* __restrict__ flag,
                        int* __restrict__ hist, int E, int n, int NB, int NBUK, int shiftv) {
    __shared__ int lh[256];
    int blk = blockIdx.x;
    for (int b = threadIdx.x; b < NBUK; b += 256) lh[b] = 0;
    __syncthreads();
    int e0 = blk * CH;
    int e1 = min(e0 + CH, E);
    int i64 = flag[0];
    for (int e = e0 + threadIdx.x; e < e1; e += 256) {
        int d;
        if (i64) d = (int)((const long long*)ei)[(size_t)E + e];
        else     d = ei[(size_t)E + e];
        int b = ((unsigned)d < (unsigned)n) ? min(d >> shiftv, NBUK - 1) : (NBUK - 1);
        atomicAdd(&lh[b], 1);
    }
    __syncthreads();
    for (int b = threadIdx.x; b < NBUK; b += 256) hist[b * NB + blk] = lh[b];
}

// generic block-scan (also reused for node-degree scan)
__global__ void scan1_k(const int* __restrict__ counts, int* incl, int* bsum, int n) {
    __shared__ int tmp[SCAN_B];
    int t = threadIdx.x;
    int i = blockIdx.x * SCAN_B + t;
    int v = (i < n) ? counts[i] : 0;
    tmp[t] = v;
    __syncthreads();
    for (int o = 1; o < SCAN_B; o <<= 1) {
        int x = 0;
        if (t >= o) x = tmp[t - o];
        __syncthreads();
        if (t >= o) tmp[t] += x;
        __syncthreads();
    }
    if (i < n) incl[i] = tmp[t];
    if (t == SCAN_B - 1) bsum[blockIdx.x] = tmp[t];
}

__global__ void scan2_k(const int* __restrict__ bsum, int* bscan, int nb) {
    __shared__ int tmp[SCAN_B];
    int t = threadIdx.x;
    tmp[t] = (t < nb) ? bsum[t] : 0;
    __syncthreads();
    for (int o = 1; o < SCAN_B; o <<= 1) {
        int x = 0;
        if (t >= o) x = tmp[t - o];
        __syncthreads();
        if (t >= o) tmp[t] += x;
        __syncthreads();
    }
    bscan[t] = tmp[t];
}

// Pass B epilogue: exclusive offsets ofs[i] = inclusive[i] + blockoff - hist[i]
__global__ void exclA_k(const int* __restrict__ incl, const int* __restrict__ bscan,
                        const int* __restrict__ hist, int* __restrict__ ofs, int len) {
    int i = blockIdx.x * 256 + threadIdx.x;
    if (i < len) {
        int boff = (blockIdx.x > 0) ? bscan[blockIdx.x - 1] : 0;
        ofs[i] = incl[i] + boff - hist[i];
    }
}

// Pass C: bucket-scatter packed (src,dst) pairs via LDS cursors (+ degree count fused)
__global__ void scatC_k(const int* __restrict__ ei, const int* __restrict__ flag,
                        const int* __restrict__ ofs, long long* __restrict__ ebuf,
                        int* __restrict__ counts,
                        int E, int n, int NB, int NBUK, int shiftv) {
    __shared__ int cur[256];
    int blk = blockIdx.x;
    for (int b = threadIdx.x; b < NBUK; b += 256) cur[b] = ofs[b * NB + blk];
    __syncthreads();
    int e0 = blk * CH;
    int e1 = min(e0 + CH, E);
    int i64 = flag[0];
    for (int e = e0 + threadIdx.x; e < e1; e += 256) {
        int s, d;
        if (i64) {
            const long long* e64 = (const long long*)ei;
            s = (int)e64[e]; d = (int)e64[(size_t)E + e];
        } else {
            s = ei[e]; d = ei[(size_t)E + e];
        }
        int b = ((unsigned)d < (unsigned)n) ? min(d >> shiftv, NBUK - 1) : (NBUK - 1);
        int pos = atomicAdd(&cur[b], 1);
        ebuf[pos] = ((long long)(unsigned)d << 32) | (unsigned)s;
        if ((unsigned)d < (unsigned)n) atomicAdd(&counts[d], 1);
    }
}

// fused CSR epilogue: rowptr + cursor + dinv in one pass (grid = NB x SCAN_B)
__global__ void finCSR_k(const int* __restrict__ incl, const int* __restrict__ bscan,
                         const int* __restrict__ counts, int* __restrict__ rowptr,
                         int* __restrict__ cursor, float* __restrict__ dinv, int n) {
    int i = blockIdx.x * SCAN_B + threadIdx.x;
    if (i < n) {
        int boff = (blockIdx.x > 0) ? bscan[blockIdx.x - 1] : 0;
        int rp_end = incl[i] + boff;         // inclusive scan = row end
        rowptr[i + 1] = rp_end;
        if (i == 0) rowptr[0] = 0;
        cursor[i] = rp_end - counts[i];      // row start, no read-after-write hazard
        dinv[i] = rsqrtf((float)counts[i]);
    }
}

// Pass D: final CSR scatter from bucket-sorted pairs (dense col-window writes)
__global__ void scatD_k(const long long* __restrict__ ebuf, int* cursor,
                        int* __restrict__ col, int E, int n) {
    int e = blockIdx.x * blockDim.x + threadIdx.x;
    if (e < E) {
        long long pr = ebuf[e];
        int d = (int)(pr >> 32);
        int s = (int)(pr & 0xffffffffLL);
        if ((unsigned)s < (unsigned)n && (unsigned)d < (unsigned)n) {
            int pos = atomicAdd(&cursor[d], 1);
            col[pos] = s;
        }
    } else if (e < E + n) {
        int i = e - E;
        int pos = atomicAdd(&cursor[i], 1);
        col[pos] = i;
    }
}

// ---------------- bf16 MFMA GEMM (m97 structure): C[M,Nn] = A[M,K] * Bt[Nn,K]^T -------
// 128x128 tile, BK=32, 4 waves x (4x4 16x16 fragments), global_load_lds width-16.
// 1D grid with XCD-aware bijective remap [T1, m204]: the ny blocks sharing one
// 128-row A-panel land on the SAME XCD -> A-panel L2-resident, fetched ~1x not ny x.
typedef __attribute__((address_space(1))) const void gas_v;
typedef __attribute__((address_space(3))) void las_v;

__global__ __launch_bounds__(256) void gemm128_k(
    const u16* __restrict__ A, const u16* __restrict__ Bt,
    u16* __restrict__ C, int M, int K, int Nn, int nyv) {
    int nx = (M + 127) >> 7;
    int nfull = nx & ~7;
    int cutoff = nfull * nyv;
    int b = blockIdx.x;
    int bx, by;
    if (b < cutoff) {
        int k = b & 7;            // XCD id (blockIdx % 8 round-robin [m09])
        int q = b >> 3;
        by = q % nyv;
        bx = (q / nyv) * 8 + k;   // all ny blocks of panel bx share XCD k
    } else {
        int r = b - cutoff;
        bx = nfull + r / nyv;
        by = r % nyv;
    }

    __shared__ u16 As[128 * 32];
    __shared__ u16 Bs[128 * 32];
    int tid = threadIdx.x;
    int wave = tid >> 6;
    int lane = tid & 63;
    int wr = (wave >> 1) * 64;   // wave row offset in tile
    int wc = (wave & 1) * 64;    // wave col offset in tile
    long row0 = (long)bx * 128;
    int col0 = by * 128;
    int lr = lane >> 2;          // 0..15 : row within 16-row staging chunk
    int lc = lane & 3;           // 0..3  : 16B column chunk
    int m = lane & 15;
    int q = lane >> 4;

    f32x4 acc[4][4];
    #pragma unroll
    for (int i = 0; i < 4; i++)
        #pragma unroll
        for (int j = 0; j < 4; j++) acc[i][j] = (f32x4){0.f, 0.f, 0.f, 0.f};

    for (int k0 = 0; k0 < K; k0 += 32) {
        // stage A,B tiles: 8 chunks of 16 rows each; wave w handles chunks w and w+4.
        // LDS is linear [128][32] bf16 (64B/row): chunk c occupies bytes
        // [c*1024, c*1024+1024), lane l writes base + l*16 == row-major position. [m97]
        #pragma unroll
        for (int p = 0; p < 2; p++) {
            int c = wave + p * 4;
            long ar = row0 + c * 16 + lr;
            if (ar > (long)M - 1) ar = (long)M - 1;  // clamp: garbage feeds masked rows only
            const u16* ga = A + ar * K + k0 + lc * 8;
            __builtin_amdgcn_global_load_lds((gas_v*)ga, (las_v*)&As[c * 512], 16, 0, 0);
            int br = col0 + c * 16 + lr;             // Nn % 128 == 0, always in-bounds
            const u16* gb = Bt + (size_t)br * K + k0 + lc * 8;
            __builtin_amdgcn_global_load_lds((gas_v*)gb, (las_v*)&Bs[c * 512], 16, 0, 0);
        }
        __syncthreads();   // compiler drains vmcnt before s_barrier

        us8 av[4], bv[4];
        #pragma unroll
        for (int i = 0; i < 4; i++) {
            av[i] = *(const us8*)&As[(wr + i * 16 + m) * 32 + q * 8];
            bv[i] = *(const us8*)&Bs[(wc + i * 16 + m) * 32 + q * 8];
        }
        #pragma unroll
        for (int i = 0; i < 4; i++) {
            bf8 fa = __builtin_bit_cast(bf8, av[i]);
            #pragma unroll
            for (int j = 0; j < 4; j++) {
                bf8 fb = __builtin_bit_cast(bf8, bv[j]);
                acc[i][j] = __builtin_amdgcn_mfma_f32_16x16x32_bf16(fa, fb, acc[i][j], 0, 0, 0);
            }
        }
        __syncthreads();
    }

    // C/D layout: col = lane&15, row = (lane>>4)*4 + r  [measured m89]
    #pragma unroll
    for (int i = 0; i < 4; i++) {
        #pragma unroll
        for (int r = 0; r < 4; r++) {
            long row = row0 + wr + i * 16 + q * 4 + r;
            if (row < M) {
                #pragma unroll
                for (int j = 0; j < 4; j++)
                    C[row * Nn + col0 + wc + j * 16 + m] = f2bf(acc[i][j][r]);
            }
        }
    }
}

// ---------------- wave-per-node aggregate [+ bias + LN + ELU (+resid) (+classifier)] ---
// 2-deep unroll: agg is fetch-throughput-bound (dur = FETCH/3.5TB/s); deeper
// unroll measured -8% (r1 post-mortem) from tail overhead at mean degree ~33.
__global__ __launch_bounds__(256) void agg_k(
    const u16* __restrict__ in, const int* __restrict__ rowptr,
    const int* __restrict__ col, const float* __restrict__ dinv,
    const float* __restrict__ bias, const float* __restrict__ gamma,
    const float* __restrict__ beta, u16* __restrict__ out_h,
    const u16* __restrict__ resid, void* __restrict__ final_base,
    const int* __restrict__ flag, const float* __restrict__ Wcf,
    const float* __restrict__ bcf, int F, int nN) {
    int wv = threadIdx.x >> 6;
    int lane = threadIdx.x & 63;
    int i = blockIdx.x * 4 + wv;
    if (i >= nN) return;

    int rowt = F >> 3;                    // 32 (F=256) or 16 (F=128)
    int Gw = 64 / rowt;                   // 2 or 4 edge groups per wave
    int g = lane / rowt;
    int f0 = (lane & (rowt - 1)) << 3;

    int beg = rowptr[i], end = rowptr[i + 1];
    f32x8 acc = {0, 0, 0, 0, 0, 0, 0, 0}, acc2 = acc;
    int e = beg + g;
    for (; e + Gw < end; e += 2 * Gw) {
        int s0 = col[e], s1 = col[e + Gw];
        s0 = ((unsigned)s0 < (unsigned)nN) ? s0 : 0;
        s1 = ((unsigned)s1 < (unsigned)nN) ? s1 : 0;
        float w0 = dinv[s0], w1 = dinv[s1];
        us8 v0 = *(const us8*)(in + (unsigned)(s0 * F) + f0);
        us8 v1 = *(const us8*)(in + (unsigned)(s1 * F) + f0);
        fma8(acc, w0, v0);
        fma8(acc2, w1, v1);
    }
    if (e < end) {
        int s = col[e];
        s = ((unsigned)s < (unsigned)nN) ? s : 0;
        us8 v = *(const us8*)(in + (unsigned)(s * F) + f0);
        fma8(acc, dinv[s], v);
    }
    #pragma unroll
    for (int j = 0; j < 8; j++) acc[j] += acc2[j];

    for (int o = 32; o >= rowt; o >>= 1) {
        #pragma unroll
        for (int j = 0; j < 8; j++) acc[j] += __shfl_down(acc[j], o);
    }
    bool active = lane < rowt;
    float di = dinv[i];

    if (!bias) {  // plain mode (layer-2 pre-aggregate)
        if (active) {
            us8 o8;
            #pragma unroll
            for (int j = 0; j < 8; j++) o8[j] = f2bf(di * acc[j]);
            *(us8*)(out_h + (unsigned)(i * F) + f0) = o8;
        }
        return;
    }

    f32x8 accv = {0, 0, 0, 0, 0, 0, 0, 0};
    if (active) {
        #pragma unroll
        for (int j = 0; j < 8; j++) accv[j] = di * acc[j] + bias[f0 + j];
    }
    int f32m = final_base ? flag[1] : 0;
    if (final_base && active) {
        size_t conv_idx = (size_t)nN * 4 + (size_t)i * F + f0;
        if (f32m) {
            #pragma unroll
            for (int j = 0; j < 8; j++) ((float*)final_base)[conv_idx + j] = accv[j];
        } else {
            us8 o8;
            #pragma unroll
            for (int j = 0; j < 8; j++) o8[j] = f2bf(accv[j]);
            *(us8*)((u16*)final_base + conv_idx) = o8;
        }
    }

    float p1 = 0.f, p2 = 0.f;
    #pragma unroll
    for (int j = 0; j < 8; j++) { p1 += accv[j]; p2 += accv[j] * accv[j]; }
    for (int o = rowt >> 1; o >= 1; o >>= 1) {
        p1 += __shfl_xor(p1, o);
        p2 += __shfl_xor(p2, o);
    }
    float invF = 1.0f / (float)F;
    float mu = p1 * invF;
    float var = fmaxf(p2 * invF - mu * mu, 0.f);
    float rstd = rsqrtf(var + 1e-5f);

    f32x8 h8 = {0, 0, 0, 0, 0, 0, 0, 0};
    if (active) {
        f32x8 y8;
        #pragma unroll
        for (int j = 0; j < 8; j++)
            y8[j] = (accv[j] - mu) * rstd * gamma[f0 + j] + beta[f0 + j];
        if (final_base) {
            size_t bn_idx = (size_t)nN * 4 + (size_t)nN * F + (size_t)i * F + f0;
            if (f32m) {
                #pragma unroll
                for (int j = 0; j < 8; j++) ((float*)final_base)[bn_idx + j] = y8[j];
            } else {
                us8 o8;
                #pragma unroll
                for (int j = 0; j < 8; j++) o8[j] = f2bf(y8[j]);
                *(us8*)((u16*)final_base + bn_idx) = o8;
            }
        }
        #pragma unroll
        for (int j = 0; j < 8; j++) h8[j] = (y8[j] > 0.f) ? y8[j] : expm1f(y8[j]);
        if (resid) {
            us8 r8 = *(const us8*)(resid + (unsigned)(i * F) + f0);
            #pragma unroll
            for (int j = 0; j < 8; j++) h8[j] += bf2f(r8[j]);
        }
        if (out_h) {
            us8 o8;
            #pragma unroll
            for (int j = 0; j < 8; j++) o8[j] = f2bf(h8[j]);
            *(us8*)(out_h + (unsigned)(i * F) + f0) = o8;
        }
    }

    if (Wcf) {
        float s0 = 0.f, s1 = 0.f, s2 = 0.f, s3 = 0.f;
        if (active) {
            #pragma unroll
            for (int j = 0; j < 8; j++) {
                const float* wr = Wcf + (f0 + j) * 4;
                s0 += h8[j] * wr[0];
                s1 += h8[j] * wr[1];
                s2 += h8[j] * wr[2];
                s3 += h8[j] * wr[3];
            }
        }
        for (int o = rowt >> 1; o >= 1; o >>= 1) {
            s0 += __shfl_xor(s0, o);
            s1 += __shfl_xor(s1, o);
            s2 += __shfl_xor(s2, o);
            s3 += __shfl_xor(s3, o);
        }
        if (lane == 0) {
            size_t lidx = (size_t)i * 4;
            if (f32m) {
                ((float*)final_base)[lidx + 0] = s0 + bcf[0];
                ((float*)final_base)[lidx + 1] = s1 + bcf[1];
                ((float*)final_base)[lidx + 2] = s2 + bcf[2];
                ((float*)final_base)[lidx + 3] = s3 + bcf[3];
            } else {
                ((u16*)final_base)[lidx + 0] = f2bf(s0 + bcf[0]);
                ((u16*)final_base)[lidx + 1] = f2bf(s1 + bcf[1]);
                ((u16*)final_base)[lidx + 2] = f2bf(s2 + bcf[2]);
                ((u16*)final_base)[lidx + 3] = f2bf(s3 + bcf[3]);
            }
        }
    }
}

// ---------------- bias + LayerNorm + ELU in place, wave-per-node, F=512 ----------
__global__ __launch_bounds__(256) void ln_elu_k(u16* __restrict__ h,
                                                const float* __restrict__ bias,
                                                const float* __restrict__ gamma,
                                                const float* __restrict__ beta, int nN) {
    int wv = threadIdx.x >> 6;
    int lane = threadIdx.x & 63;
    int i = blockIdx.x * 4 + wv;
    if (i >= nN) return;
    int f0 = lane * 8;                       // 64 lanes x 8 = 512 features
    size_t base = (size_t)i * 512 + f0;
    us8 v8 = *(const us8*)(h + base);
    f32x8 v;
    #pragma unroll
    for (int j = 0; j < 8; j++) v[j] = bf2f(v8[j]) + bias[f0 + j];
    float p1 = 0.f, p2 = 0.f;
    #pragma unroll
    for (int j = 0; j < 8; j++) { p1 += v[j]; p2 += v[j] * v[j]; }
    #pragma unroll
    for (int o = 32; o >= 1; o >>= 1) {
        p1 += __shfl_xor(p1, o);
        p2 += __shfl_xor(p2, o);
    }
    const float invF = 1.0f / 512.0f;
    float mu = p1 * invF;
    float var = fmaxf(p2 * invF - mu * mu, 0.f);
    float rstd = rsqrtf(var + 1e-5f);
    us8 o8;
    #pragma unroll
    for (int j = 0; j < 8; j++) {
        float y = (v[j] - mu) * rstd * gamma[f0 + j] + beta[f0 + j];
        y = (y > 0.f) ? y : expm1f(y);
        o8[j] = f2bf(y);
    }
    *(us8*)(h + base) = o8;
}

// ---------------- ws-too-small marker ----------------
__global__ void marker_k(float* out) {
    if (threadIdx.x == 0 && blockIdx.x == 0) {
        out[0] = 31337.0f; out[1] = 31337.0f;
    }
}

extern "C" void kernel_launch(void* const* d_in, const int* in_sizes, int n_in,
                              void* d_out, int out_size, void* d_ws, size_t ws_size,
                              hipStream_t stream) {
    const int N = in_sizes[0] / 512;   // 50000
    const int E = in_sizes[1] / 2;     // 1600000

    const void* x  = d_in[0];
    const int* ei  = (const int*)d_in[1];

    // ---- workspace carve ----
    char* p = (char*)d_ws;
    auto alloc = [&](size_t bytes) -> void* {
        void* r = (void*)p;
        p += (bytes + 255) & ~(size_t)255;
        return r;
    };
    int*   flag   = (int*)alloc(256);
    int*   counts = (int*)alloc((size_t)N * 4);
    int*   rowptr = (int*)alloc((size_t)(N + 1) * 4);
    int*   cursor = (int*)alloc((size_t)N * 4);
    int*   incl   = (int*)alloc((size_t)N * 4);
    int*   bsum   = (int*)alloc(256 * 4);
    int*   bscan  = (int*)alloc(256 * 4);
    float* dinv   = (float*)alloc((size_t)N * 4);
    int*   col    = (int*)alloc((size_t)(E + N) * 4);
    float* pbuf   = (float*)alloc(4096 * 4);
    u16* W1t = (u16*)alloc((size_t)512 * 256 * 2);
    u16* W2t = (u16*)alloc((size_t)256 * 512 * 2);
    u16* W3t = (u16*)alloc((size_t)512 * 256 * 2);
    u16* W4t = (u16*)alloc((size_t)256 * 128 * 2);
    u16* bigA = (u16*)alloc((size_t)N * 512 * 2);  // xbf -> h2
    u16* xw   = (u16*)alloc((size_t)N * 256 * 2);  // ebuf (CSR build) -> GEMM scratch
    u16* h1   = (u16*)alloc((size_t)N * 256 * 2);  // hist arrays (CSR build) -> h1

    size_t needed = (size_t)(p - (char*)d_ws);
    if (needed > ws_size) {
        marker_k<<<1, 64, 0, stream>>>((float*)d_out);
        return;
    }

    u16* xbf = bigA;
    u16* h2  = bigA;  // [N,512], alive after xbf dead

    // bucket-sort params (dead buffers aliased; all CSR work precedes their next use)
    int shiftv = 8;
    while (((N - 1) >> shiftv) > 255) shiftv++;
    int NBUK = ((N - 1) >> shiftv) + 1;            // 196 for N=50000
    int NB_E = (E + CH - 1) / CH;                  // 196 for E=1.6M
    int flatlen = NBUK * NB_E;                     // ~38k
    int NH = (flatlen + 255) / 256;                // <=256 required
    long long* ebuf = (long long*)xw;              // E*8 B <= N*256*2 B
    int* hist     = (int*)h1;
    int* histincl = hist + flatlen;
    int* ofs      = histincl + flatlen;

    PTab tab;
    tab.e[0]  = { d_in[3],  256, 0    };  // b1
    tab.e[1]  = { d_in[12], 256, 256  };  // g1
    tab.e[2]  = { d_in[13], 256, 512  };  // be1
    tab.e[3]  = { d_in[5],  512, 768  };  // b2
    tab.e[4]  = { d_in[14], 512, 1280 };  // g2
    tab.e[5]  = { d_in[15], 512, 1792 };  // be2
    tab.e[6]  = { d_in[7],  256, 2304 };  // b3
    tab.e[7]  = { d_in[16], 256, 2560 };  // g3
    tab.e[8]  = { d_in[17], 256, 2816 };  // be3
    tab.e[9]  = { d_in[9],  128, 3072 };  // b4
    tab.e[10] = { d_in[18], 128, 3200 };  // g4
    tab.e[11] = { d_in[19], 128, 3328 };  // be4
    tab.e[12] = { d_in[10], 512, 3456 };  // Wc
    tab.e[13] = { d_in[11], 4,   3968 };  // bc
    float* b1f = pbuf + 0,   *g1f = pbuf + 256,  *be1f = pbuf + 512;
    float* b2f = pbuf + 768, *g2f = pbuf + 1280, *be2f = pbuf + 1792;
    float* b3f = pbuf + 2304,*g3f = pbuf + 2560, *be3f = pbuf + 2816;
    float* b4f = pbuf + 3072,*g4f = pbuf + 3200, *be4f = pbuf + 3328;
    float* Wcf = pbuf + 3456,*bcf = pbuf + 3968;

    int nb1 = (N + 255) / 256;
    int NB = (N + SCAN_B - 1) / SCAN_B;

    // ---- dtype probes ----
    detect_k<<<1, 256, 0, stream>>>(ei, E, (const u16*)x, flag);

    // ---- canonicalize ----
    cvt_x_k<<<4096, 256, 0, stream>>>(x, xbf, (long)N * 512 / 4, flag);
    {
        WEnt e0 = { d_in[2], W1t, 512, 256, 0 };
        WEnt e1 = { d_in[4], W2t, 256, 512, 512 * 256 };
        WEnt e2 = { d_in[6], W3t, 512, 256, 512 * 256 + 256 * 512 };
        WEnt e3 = { d_in[8], W4t, 256, 128, 512 * 256 * 2 + 256 * 512 };
        int total = 512 * 256 * 2 + 256 * 512 + 256 * 128;
        cvt_wts_k<<<(total + 255) / 256, 256, 0, stream>>>(e0, e1, e2, e3, flag, total);
    }
    cvt_params_k<<<14, 256, 0, stream>>>(tab, pbuf, flag);

    // ---- CSR build (bucket-sorted) ----
    init_counts_k<<<nb1, 256, 0, stream>>>(counts, N);
    histA_k<<<NB_E, 256, 0, stream>>>(ei, flag, hist, E, N, NB_E, NBUK, shiftv);
    scan1_k<<<NH, SCAN_B, 0, stream>>>(hist, histincl, bsum, flatlen);
    scan2_k<<<1, SCAN_B, 0, stream>>>(bsum, bscan, NH);
    exclA_k<<<NH, 256, 0, stream>>>(histincl, bscan, hist, ofs, flatlen);
    scatC_k<<<NB_E, 256, 0, stream>>>(ei, flag, ofs, ebuf, counts, E, N, NB_E, NBUK, shiftv);
    scan1_k<<<NB, SCAN_B, 0, stream>>>(counts, incl, bsum, N);
    scan2_k<<<1, SCAN_B, 0, stream>>>(bsum, bscan, NB);
    finCSR_k<<<NB, SCAN_B, 0, stream>>>(incl, bscan, counts, rowptr, cursor, dinv, N);
    scatD_k<<<(E + N + 255) / 256, 256, 0, stream>>>(ebuf, cursor, col, E, N);

    int gx = (N + 127) / 128;          // 391
    int ga = (N + 3) / 4;

    // ---- layer 1: xbf[N,512] @ W1 -> agg+LN+ELU -> h1[N,256] ----
    gemm128_k<<<gx * 2, 256, 0, stream>>>(xbf, W1t, xw, N, 512, 256, 2);
    agg_k<<<ga, 256, 0, stream>>>(xw, rowptr, col, dinv, b1f, g1f, be1f,
                                  h1, nullptr, nullptr, flag, nullptr, nullptr, 256, N);
    // ---- layer 2 (agg BEFORE GEMM: agg(h1 @ W2) == agg(h1) @ W2) ----
    agg_k<<<ga, 256, 0, stream>>>(h1, rowptr, col, dinv, nullptr, nullptr, nullptr,
                                  xw, nullptr, nullptr, flag, nullptr, nullptr, 256, N);
    gemm128_k<<<gx * 4, 256, 0, stream>>>(xw, W2t, h2, N, 256, 512, 4);
    ln_elu_k<<<ga, 256, 0, stream>>>(h2, b2f, g2f, be2f, N);
    // ---- layer 3: h2[N,512] @ W3 -> agg+LN+ELU + h1 -> h1[N,256] ----
    gemm128_k<<<gx * 2, 256, 0, stream>>>(h2, W3t, xw, N, 512, 256, 2);
    agg_k<<<ga, 256, 0, stream>>>(xw, rowptr, col, dinv, b3f, g3f, be3f,
                                  h1, h1, nullptr, flag, nullptr, nullptr, 256, N);
    // ---- layer 4: h1[N,256] @ W4 -> agg -> out_conv/out_bn + fused classifier ----
    gemm128_k<<<gx * 1, 256, 0, stream>>>(h1, W4t, xw, N, 256, 128, 1);
    agg_k<<<ga, 256, 0, stream>>>(xw, rowptr, col, dinv, b4f, g4f, be4f,
                                  nullptr, nullptr, d_out, flag, Wcf, bcf, 128, N);
}

// Round 4
// 970.568 us; speedup vs baseline: 1.0330x; 1.0141x over previous
//
#include <hip/hip_runtime.h>
#include <hip/hip_bf16.h>
#include <math.h>

typedef unsigned short u16;
typedef u16 us8 __attribute__((ext_vector_type(8)));
typedef u16 us4 __attribute__((ext_vector_type(4)));
typedef float f32x4 __attribute__((ext_vector_type(4)));
typedef float f32x8 __attribute__((ext_vector_type(8)));
typedef __bf16 bf8 __attribute__((ext_vector_type(8)));

#define SCAN_B 256
#define CH 8192   // edges per bucket-sort block

__device__ __forceinline__ float bf2f(u16 v) {
    unsigned u = ((unsigned)v) << 16;
    return __builtin_bit_cast(float, u);
}
__device__ __forceinline__ u16 f2bf(float f) {
    unsigned u = __builtin_bit_cast(unsigned, f);
    unsigned lsb = (u >> 16) & 1;
    u += 0x7fff + lsb;
    return (u16)(u >> 16);
}
__device__ __forceinline__ void fma8(f32x8& acc, float w, us8 v) {
#pragma unroll
    for (int j = 0; j < 8; j++) acc[j] += w * bf2f(v[j]);
}

// ---------------- runtime dtype probes ----------------
__global__ void detect_k(const int* __restrict__ ei, int E,
                         const u16* __restrict__ xraw, int* flag) {
    __shared__ int c_i32, c_f32;
    if (threadIdx.x == 0) { c_i32 = 0; c_f32 = 0; }
    __syncthreads();
    int ne = (E < 4096) ? E : 4096;
    for (int e = threadIdx.x; e < ne; e += blockDim.x)
        if (ei[2 * e + 1] != 0) c_i32 = 1;
    for (int k = threadIdx.x; k < 8192; k += blockDim.x) {
        u16 v = xraw[2 * k];
        int ex = (v >> 7) & 0xFF;
        if (ex >= 0xF0) atomicAdd(&c_f32, 1);
    }
    __syncthreads();
    if (threadIdx.x == 0) {
        flag[0] = (c_i32 == 0) ? 1 : 0;
        flag[1] = (c_f32 >= 4) ? 1 : 0;
    }
}

// ---------------- merged canonicalize: x + 4 weight transposes + params ----------
struct WEnt { const void* s; u16* dst; int K; int Nn; int base; };
struct PEnt { const void* s; int n; int off; };
struct PTab { PEnt e[14]; };

#define GX_CVT 4096

__global__ void megacvt_k(const void* __restrict__ xsrc, u16* __restrict__ xdst,
                          long nq, WEnt e0, WEnt e1, WEnt e2, WEnt e3, int wtotal,
                          PTab tab, float* __restrict__ pbuf,
                          const int* __restrict__ flag, int gw) {
    int f32m = flag[1];
    int bid = blockIdx.x;
    if (bid < GX_CVT) {                 // ---- x convert (grid-stride) ----
        long i0 = (long)bid * blockDim.x + threadIdx.x;
        long stride = (long)GX_CVT * blockDim.x;
        if (f32m) {
            const f32x4* s = (const f32x4*)xsrc;
            for (long i = i0; i < nq; i += stride) {
                f32x4 v = s[i];
                us4 o;
                #pragma unroll
                for (int j = 0; j < 4; j++) o[j] = f2bf(v[j]);
                ((us4*)xdst)[i] = o;
            }
        } else {
            const us4* s = (const us4*)xsrc;
            for (long i = i0; i < nq; i += stride) ((us4*)xdst)[i] = s[i];
        }
    } else if (bid < GX_CVT + gw) {     // ---- weight transpose+convert ----
        int t = (bid - GX_CVT) * blockDim.x + threadIdx.x;
        if (t >= wtotal) return;
        WEnt en = (t >= e3.base) ? e3 : ((t >= e2.base) ? e2 : ((t >= e1.base) ? e1 : e0));
        int li = t - en.base;
        int k = li / en.Nn, nn = li - k * en.Nn;
        u16 b;
        if (f32m) b = f2bf(((const float*)en.s)[li]);
        else      b = ((const u16*)en.s)[li];
        en.dst[nn * en.K + k] = b;
    } else {                            // ---- small params -> f32 ----
        PEnt en = tab.e[bid - GX_CVT - gw];
        for (int i = threadIdx.x; i < en.n; i += blockDim.x) {
            float v = f32m ? ((const float*)en.s)[i] : bf2f(((const u16*)en.s)[i]);
            pbuf[en.off + i] = v;
        }
    }
}

// ---------------- CSR build (bucket-sorted, low write-amplification) ----------------
// Pass A: per-block bucket histogram (bucket = dst >> shiftv) + counts init fused
__global__ void histA_k(const int* __restrict__ ei, const int* __restrict__ flag,
                        int* __restrict__ hist, int* __restrict__ counts,
                        int E, int n, int NB, int NBUK, int shiftv) {
    __shared__ int lh[256];
    int blk = blockIdx.x;
    int gi = blk * 256 + threadIdx.x;   // NB*256 >= n guaranteed (NB>=196)
    if (gi < n) counts[gi] = 1;         // self-loop init (consumed later by scatC)
    for (int b = threadIdx.x; b < NBUK; b += 256) lh[b] = 0;
    __syncthreads();
    int e0 = blk * CH;
    int e1 = min(e0 + CH, E);
    int i64 = flag[0];
    for (int e = e0 + threadIdx.x; e < e1; e += 256) {
        int d;
        if (i64) d = (int)((const long long*)ei)[(size_t)E + e];
        else     d = ei[(size_t)E + e];
        int b = ((unsigned)d < (unsigned)n) ? min(d >> shiftv, NBUK - 1) : (NBUK - 1);
        atomicAdd(&lh[b], 1);
    }
    __syncthreads();
    for (int b = threadIdx.x; b < NBUK; b += 256) hist[b * NB + blk] = lh[b];
}

// generic block-scan (also reused for node-degree scan)
__global__ void scan1_k(const int* __restrict__ counts, int* incl, int* bsum, int n) {
    __shared__ int tmp[SCAN_B];
    int t = threadIdx.x;
    int i = blockIdx.x * SCAN_B + t;
    int v = (i < n) ? counts[i] : 0;
    tmp[t] = v;
    __syncthreads();
    for (int o = 1; o < SCAN_B; o <<= 1) {
        int x = 0;
        if (t >= o) x = tmp[t - o];
        __syncthreads();
        if (t >= o) tmp[t] += x;
        __syncthreads();
    }
    if (i < n) incl[i] = tmp[t];
    if (t == SCAN_B - 1) bsum[blockIdx.x] = tmp[t];
}

__global__ void scan2_k(const int* __restrict__ bsum, int* bscan, int nb) {
    __shared__ int tmp[SCAN_B];
    int t = threadIdx.x;
    tmp[t] = (t < nb) ? bsum[t] : 0;
    __syncthreads();
    for (int o = 1; o < SCAN_B; o <<= 1) {
        int x = 0;
        if (t >= o) x = tmp[t - o];
        __syncthreads();
        if (t >= o) tmp[t] += x;
        __syncthreads();
    }
    bscan[t] = tmp[t];
}

// Pass C: bucket-scatter packed (src,dst) pairs via LDS cursors.
// Cursor computed inline (exclA fused): ofs(fi) = histincl[fi] + bscan_prev - hist[fi].
__global__ void scatC_k(const int* __restrict__ ei, const int* __restrict__ flag,
                        const int* __restrict__ histincl, const int* __restrict__ bscan,
                        const int* __restrict__ hist, long long* __restrict__ ebuf,
                        int* __restrict__ counts,
                        int E, int n, int NB, int NBUK, int shiftv) {
    __shared__ int cur[256];
    int blk = blockIdx.x;
    for (int b = threadIdx.x; b < NBUK; b += 256) {
        int fi = b * NB + blk;
        int boff = (fi >= 256) ? bscan[(fi >> 8) - 1] : 0;
        cur[b] = histincl[fi] + boff - hist[fi];
    }
    __syncthreads();
    int e0 = blk * CH;
    int e1 = min(e0 + CH, E);
    int i64 = flag[0];
    for (int e = e0 + threadIdx.x; e < e1; e += 256) {
        int s, d;
        if (i64) {
            const long long* e64 = (const long long*)ei;
            s = (int)e64[e]; d = (int)e64[(size_t)E + e];
        } else {
            s = ei[e]; d = ei[(size_t)E + e];
        }
        int b = ((unsigned)d < (unsigned)n) ? min(d >> shiftv, NBUK - 1) : (NBUK - 1);
        int pos = atomicAdd(&cur[b], 1);
        ebuf[pos] = ((long long)(unsigned)d << 32) | (unsigned)s;
        if ((unsigned)d < (unsigned)n) atomicAdd(&counts[d], 1);
    }
}

// fused CSR epilogue: rowptr + cursor + dinv in one pass (grid = NB x SCAN_B)
__global__ void finCSR_k(const int* __restrict__ incl, const int* __restrict__ bscan,
                         const int* __restrict__ counts, int* __restrict__ rowptr,
                         int* __restrict__ cursor, float* __restrict__ dinv, int n) {
    int i = blockIdx.x * SCAN_B + threadIdx.x;
    if (i < n) {
        int boff = (blockIdx.x > 0) ? bscan[blockIdx.x - 1] : 0;
        int rp_end = incl[i] + boff;         // inclusive scan = row end
        rowptr[i + 1] = rp_end;
        if (i == 0) rowptr[0] = 0;
        cursor[i] = rp_end - counts[i];      // row start, no read-after-write hazard
        dinv[i] = rsqrtf((float)counts[i]);
    }
}

// Pass D: final CSR scatter from bucket-sorted pairs (dense col-window writes)
__global__ void scatD_k(const long long* __restrict__ ebuf, int* cursor,
                        int* __restrict__ col, int E, int n) {
    int e = blockIdx.x * blockDim.x + threadIdx.x;
    if (e < E) {
        long long pr = ebuf[e];
        int d = (int)(pr >> 32);
        int s = (int)(pr & 0xffffffffLL);
        if ((unsigned)s < (unsigned)n && (unsigned)d < (unsigned)n) {
            int pos = atomicAdd(&cursor[d], 1);
            col[pos] = s;
        }
    } else if (e < E + n) {
        int i = e - E;
        int pos = atomicAdd(&cursor[i], 1);
        col[pos] = i;
    }
}

// ---------------- bf16 MFMA GEMM (m97 structure): C[M,Nn] = A[M,K] * Bt[Nn,K]^T -------
// 128x128 tile, BK=32, 4 waves x (4x4 16x16 fragments), global_load_lds width-16.
// 1D grid with XCD-aware bijective remap [T1, m204]: the ny blocks sharing one
// 128-row A-panel land on the SAME XCD -> A-panel L2-resident, fetched ~1x not ny x.
typedef __attribute__((address_space(1))) const void gas_v;
typedef __attribute__((address_space(3))) void las_v;

__global__ __launch_bounds__(256) void gemm128_k(
    const u16* __restrict__ A, const u16* __restrict__ Bt,
    u16* __restrict__ C, int M, int K, int Nn, int nyv) {
    int nx = (M + 127) >> 7;
    int nfull = nx & ~7;
    int cutoff = nfull * nyv;
    int b = blockIdx.x;
    int bx, by;
    if (b < cutoff) {
        int k = b & 7;            // XCD id (blockIdx % 8 round-robin [m09])
        int q = b >> 3;
        by = q % nyv;
        bx = (q / nyv) * 8 + k;   // all ny blocks of panel bx share XCD k
    } else {
        int r = b - cutoff;
        bx = nfull + r / nyv;
        by = r % nyv;
    }

    __shared__ u16 As[128 * 32];
    __shared__ u16 Bs[128 * 32];
    int tid = threadIdx.x;
    int wave = tid >> 6;
    int lane = tid & 63;
    int wr = (wave >> 1) * 64;   // wave row offset in tile
    int wc = (wave & 1) * 64;    // wave col offset in tile
    long row0 = (long)bx * 128;
    int col0 = by * 128;
    int lr = lane >> 2;          // 0..15 : row within 16-row staging chunk
    int lc = lane & 3;           // 0..3  : 16B column chunk
    int m = lane & 15;
    int q = lane >> 4;

    f32x4 acc[4][4];
    #pragma unroll
    for (int i = 0; i < 4; i++)
        #pragma unroll
        for (int j = 0; j < 4; j++) acc[i][j] = (f32x4){0.f, 0.f, 0.f, 0.f};

    for (int k0 = 0; k0 < K; k0 += 32) {
        #pragma unroll
        for (int p = 0; p < 2; p++) {
            int c = wave + p * 4;
            long ar = row0 + c * 16 + lr;
            if (ar > (long)M - 1) ar = (long)M - 1;  // clamp: garbage feeds masked rows only
            const u16* ga = A + ar * K + k0 + lc * 8;
            __builtin_amdgcn_global_load_lds((gas_v*)ga, (las_v*)&As[c * 512], 16, 0, 0);
            int br = col0 + c * 16 + lr;             // Nn % 128 == 0, always in-bounds
            const u16* gb = Bt + (size_t)br * K + k0 + lc * 8;
            __builtin_amdgcn_global_load_lds((gas_v*)gb, (las_v*)&Bs[c * 512], 16, 0, 0);
        }
        __syncthreads();   // compiler drains vmcnt before s_barrier

        us8 av[4], bv[4];
        #pragma unroll
        for (int i = 0; i < 4; i++) {
            av[i] = *(const us8*)&As[(wr + i * 16 + m) * 32 + q * 8];
            bv[i] = *(const us8*)&Bs[(wc + i * 16 + m) * 32 + q * 8];
        }
        #pragma unroll
        for (int i = 0; i < 4; i++) {
            bf8 fa = __builtin_bit_cast(bf8, av[i]);
            #pragma unroll
            for (int j = 0; j < 4; j++) {
                bf8 fb = __builtin_bit_cast(bf8, bv[j]);
                acc[i][j] = __builtin_amdgcn_mfma_f32_16x16x32_bf16(fa, fb, acc[i][j], 0, 0, 0);
            }
        }
        __syncthreads();
    }

    // C/D layout: col = lane&15, row = (lane>>4)*4 + r  [measured m89]
    #pragma unroll
    for (int i = 0; i < 4; i++) {
        #pragma unroll
        for (int r = 0; r < 4; r++) {
            long row = row0 + wr + i * 16 + q * 4 + r;
            if (row < M) {
                #pragma unroll
                for (int j = 0; j < 4; j++)
                    C[row * Nn + col0 + wc + j * 16 + m] = f2bf(acc[i][j][r]);
            }
        }
    }
}

// ---------------- wave-per-node aggregate [+ bias + LN + ELU (+resid) (+classifier)] ---
// F templated: s*F becomes shift, rowt/Gw constexpr (VALU addressing cut).
// 2-deep unroll: agg is L2-miss-throughput-bound (dur = FETCH/3.2TB/s, ~0.4TB/s/XCD);
// unroll-4 measured -8% (r1), deeper MLP can't help a full miss queue.
template <int F>
__global__ __launch_bounds__(256) void agg_k(
    const u16* __restrict__ in, const int* __restrict__ rowptr,
    const int* __restrict__ col, const float* __restrict__ dinv,
    const float* __restrict__ bias, const float* __restrict__ gamma,
    const float* __restrict__ beta, u16* __restrict__ out_h,
    const u16* __restrict__ resid, void* __restrict__ final_base,
    const int* __restrict__ flag, const float* __restrict__ Wcf,
    const float* __restrict__ bcf, int nN) {
    int wv = threadIdx.x >> 6;
    int lane = threadIdx.x & 63;
    int i = blockIdx.x * 4 + wv;
    if (i >= nN) return;

    constexpr int rowt = F >> 3;          // 32 (F=256) or 16 (F=128)
    constexpr int Gw = 64 / rowt;         // 2 or 4 edge groups per wave
    int g = lane / rowt;
    int f0 = (lane & (rowt - 1)) << 3;

    int beg = rowptr[i], end = rowptr[i + 1];
    f32x8 acc = {0, 0, 0, 0, 0, 0, 0, 0}, acc2 = acc;
    int e = beg + g;
    for (; e + Gw < end; e += 2 * Gw) {
        int s0 = col[e], s1 = col[e + Gw];
        s0 = ((unsigned)s0 < (unsigned)nN) ? s0 : 0;
        s1 = ((unsigned)s1 < (unsigned)nN) ? s1 : 0;
        float w0 = dinv[s0], w1 = dinv[s1];
        us8 v0 = *(const us8*)(in + (unsigned)(s0 * F) + f0);
        us8 v1 = *(const us8*)(in + (unsigned)(s1 * F) + f0);
        fma8(acc, w0, v0);
        fma8(acc2, w1, v1);
    }
    if (e < end) {
        int s = col[e];
        s = ((unsigned)s < (unsigned)nN) ? s : 0;
        us8 v = *(const us8*)(in + (unsigned)(s * F) + f0);
        fma8(acc, dinv[s], v);
    }
    #pragma unroll
    for (int j = 0; j < 8; j++) acc[j] += acc2[j];

    #pragma unroll
    for (int o = 32; o >= rowt; o >>= 1) {
        #pragma unroll
        for (int j = 0; j < 8; j++) acc[j] += __shfl_down(acc[j], o);
    }
    bool active = lane < rowt;
    float di = dinv[i];

    if (!bias) {  // plain mode (layer-2 pre-aggregate)
        if (active) {
            us8 o8;
            #pragma unroll
            for (int j = 0; j < 8; j++) o8[j] = f2bf(di * acc[j]);
            *(us8*)(out_h + (unsigned)(i * F) + f0) = o8;
        }
        return;
    }

    f32x8 accv = {0, 0, 0, 0, 0, 0, 0, 0};
    if (active) {
        #pragma unroll
        for (int j = 0; j < 8; j++) accv[j] = di * acc[j] + bias[f0 + j];
    }
    int f32m = final_base ? flag[1] : 0;
    if (final_base && active) {
        size_t conv_idx = (size_t)nN * 4 + (size_t)i * F + f0;
        if (f32m) {
            #pragma unroll
            for (int j = 0; j < 8; j++) ((float*)final_base)[conv_idx + j] = accv[j];
        } else {
            us8 o8;
            #pragma unroll
            for (int j = 0; j < 8; j++) o8[j] = f2bf(accv[j]);
            *(us8*)((u16*)final_base + conv_idx) = o8;
        }
    }

    float p1 = 0.f, p2 = 0.f;
    #pragma unroll
    for (int j = 0; j < 8; j++) { p1 += accv[j]; p2 += accv[j] * accv[j]; }
    #pragma unroll
    for (int o = rowt >> 1; o >= 1; o >>= 1) {
        p1 += __shfl_xor(p1, o);
        p2 += __shfl_xor(p2, o);
    }
    constexpr float invF = 1.0f / (float)F;
    float mu = p1 * invF;
    float var = fmaxf(p2 * invF - mu * mu, 0.f);
    float rstd = rsqrtf(var + 1e-5f);

    f32x8 h8 = {0, 0, 0, 0, 0, 0, 0, 0};
    if (active) {
        f32x8 y8;
        #pragma unroll
        for (int j = 0; j < 8; j++)
            y8[j] = (accv[j] - mu) * rstd * gamma[f0 + j] + beta[f0 + j];
        if (final_base) {
            size_t bn_idx = (size_t)nN * 4 + (size_t)nN * F + (size_t)i * F + f0;
            if (f32m) {
                #pragma unroll
                for (int j = 0; j < 8; j++) ((float*)final_base)[bn_idx + j] = y8[j];
            } else {
                us8 o8;
                #pragma unroll
                for (int j = 0; j < 8; j++) o8[j] = f2bf(y8[j]);
                *(us8*)((u16*)final_base + bn_idx) = o8;
            }
        }
        #pragma unroll
        for (int j = 0; j < 8; j++) h8[j] = (y8[j] > 0.f) ? y8[j] : expm1f(y8[j]);
        if (resid) {
            us8 r8 = *(const us8*)(resid + (unsigned)(i * F) + f0);
            #pragma unroll
            for (int j = 0; j < 8; j++) h8[j] += bf2f(r8[j]);
        }
        if (out_h) {
            us8 o8;
            #pragma unroll
            for (int j = 0; j < 8; j++) o8[j] = f2bf(h8[j]);
            *(us8*)(out_h + (unsigned)(i * F) + f0) = o8;
        }
    }

    if (Wcf) {
        float s0 = 0.f, s1 = 0.f, s2 = 0.f, s3 = 0.f;
        if (active) {
            #pragma unroll
            for (int j = 0; j < 8; j++) {
                const float* wr = Wcf + (f0 + j) * 4;
                s0 += h8[j] * wr[0];
                s1 += h8[j] * wr[1];
                s2 += h8[j] * wr[2];
                s3 += h8[j] * wr[3];
            }
        }
        #pragma unroll
        for (int o = rowt >> 1; o >= 1; o >>= 1) {
            s0 += __shfl_xor(s0, o);
            s1 += __shfl_xor(s1, o);
            s2 += __shfl_xor(s2, o);
            s3 += __shfl_xor(s3, o);
        }
        if (lane == 0) {
            size_t lidx = (size_t)i * 4;
            if (f32m) {
                ((float*)final_base)[lidx + 0] = s0 + bcf[0];
                ((float*)final_base)[lidx + 1] = s1 + bcf[1];
                ((float*)final_base)[lidx + 2] = s2 + bcf[2];
                ((float*)final_base)[lidx + 3] = s3 + bcf[3];
            } else {
                ((u16*)final_base)[lidx + 0] = f2bf(s0 + bcf[0]);
                ((u16*)final_base)[lidx + 1] = f2bf(s1 + bcf[1]);
                ((u16*)final_base)[lidx + 2] = f2bf(s2 + bcf[2]);
                ((u16*)final_base)[lidx + 3] = f2bf(s3 + bcf[3]);
            }
        }
    }
}

// ---------------- bias + LayerNorm + ELU in place, wave-per-node, F=512 ----------
__global__ __launch_bounds__(256) void ln_elu_k(u16* __restrict__ h,
                                                const float* __restrict__ bias,
                                                const float* __restrict__ gamma,
                                                const float* __restrict__ beta, int nN) {
    int wv = threadIdx.x >> 6;
    int lane = threadIdx.x & 63;
    int i = blockIdx.x * 4 + wv;
    if (i >= nN) return;
    int f0 = lane * 8;                       // 64 lanes x 8 = 512 features
    size_t base = (size_t)i * 512 + f0;
    us8 v8 = *(const us8*)(h + base);
    f32x8 v;
    #pragma unroll
    for (int j = 0; j < 8; j++) v[j] = bf2f(v8[j]) + bias[f0 + j];
    float p1 = 0.f, p2 = 0.f;
    #pragma unroll
    for (int j = 0; j < 8; j++) { p1 += v[j]; p2 += v[j] * v[j]; }
    #pragma unroll
    for (int o = 32; o >= 1; o >>= 1) {
        p1 += __shfl_xor(p1, o);
        p2 += __shfl_xor(p2, o);
    }
    const float invF = 1.0f / 512.0f;
    float mu = p1 * invF;
    float var = fmaxf(p2 * invF - mu * mu, 0.f);
    float rstd = rsqrtf(var + 1e-5f);
    us8 o8;
    #pragma unroll
    for (int j = 0; j < 8; j++) {
        float y = (v[j] - mu) * rstd * gamma[f0 + j] + beta[f0 + j];
        y = (y > 0.f) ? y : expm1f(y);
        o8[j] = f2bf(y);
    }
    *(us8*)(h + base) = o8;
}

// ---------------- ws-too-small marker ----------------
__global__ void marker_k(float* out) {
    if (threadIdx.x == 0 && blockIdx.x == 0) {
        out[0] = 31337.0f; out[1] = 31337.0f;
    }
}

extern "C" void kernel_launch(void* const* d_in, const int* in_sizes, int n_in,
                              void* d_out, int out_size, void* d_ws, size_t ws_size,
                              hipStream_t stream) {
    const int N = in_sizes[0] / 512;   // 50000
    const int E = in_sizes[1] / 2;     // 1600000

    const void* x  = d_in[0];
    const int* ei  = (const int*)d_in[1];

    // ---- workspace carve ----
    char* p = (char*)d_ws;
    auto alloc = [&](size_t bytes) -> void* {
        void* r = (void*)p;
        p += (bytes + 255) & ~(size_t)255;
        return r;
    };
    int*   flag   = (int*)alloc(256);
    int*   counts = (int*)alloc((size_t)N * 4);
    int*   rowptr = (int*)alloc((size_t)(N + 1) * 4);
    int*   cursor = (int*)alloc((size_t)N * 4);
    int*   incl   = (int*)alloc((size_t)N * 4);
    int*   bsum   = (int*)alloc(256 * 4);
    int*   bscan  = (int*)alloc(256 * 4);
    float* dinv   = (float*)alloc((size_t)N * 4);
    int*   col    = (int*)alloc((size_t)(E + N) * 4);
    float* pbuf   = (float*)alloc(4096 * 4);
    u16* W1t = (u16*)alloc((size_t)512 * 256 * 2);
    u16* W2t = (u16*)alloc((size_t)256 * 512 * 2);
    u16* W3t = (u16*)alloc((size_t)512 * 256 * 2);
    u16* W4t = (u16*)alloc((size_t)256 * 128 * 2);
    u16* bigA = (u16*)alloc((size_t)N * 512 * 2);  // xbf -> h2
    u16* xw   = (u16*)alloc((size_t)N * 256 * 2);  // ebuf (CSR build) -> GEMM scratch
    u16* h1   = (u16*)alloc((size_t)N * 256 * 2);  // hist arrays (CSR build) -> h1

    size_t needed = (size_t)(p - (char*)d_ws);
    if (needed > ws_size) {
        marker_k<<<1, 64, 0, stream>>>((float*)d_out);
        return;
    }

    u16* xbf = bigA;
    u16* h2  = bigA;  // [N,512], alive after xbf dead

    // bucket-sort params (dead buffers aliased; all CSR work precedes their next use)
    int shiftv = 8;
    while (((N - 1) >> shiftv) > 255) shiftv++;
    int NBUK = ((N - 1) >> shiftv) + 1;            // 196 for N=50000
    int NB_E = (E + CH - 1) / CH;                  // 196 for E=1.6M
    int flatlen = NBUK * NB_E;                     // ~38k
    int NH = (flatlen + 255) / 256;                // <=256 required
    long long* ebuf = (long long*)xw;              // E*8 B <= N*256*2 B
    int* hist     = (int*)h1;
    int* histincl = hist + flatlen;
    int* ofs      = histincl + flatlen;            // (unused, kept for layout)

    PTab tab;
    tab.e[0]  = { d_in[3],  256, 0    };  // b1
    tab.e[1]  = { d_in[12], 256, 256  };  // g1
    tab.e[2]  = { d_in[13], 256, 512  };  // be1
    tab.e[3]  = { d_in[5],  512, 768  };  // b2
    tab.e[4]  = { d_in[14], 512, 1280 };  // g2
    tab.e[5]  = { d_in[15], 512, 1792 };  // be2
    tab.e[6]  = { d_in[7],  256, 2304 };  // b3
    tab.e[7]  = { d_in[16], 256, 2560 };  // g3
    tab.e[8]  = { d_in[17], 256, 2816 };  // be3
    tab.e[9]  = { d_in[9],  128, 3072 };  // b4
    tab.e[10] = { d_in[18], 128, 3200 };  // g4
    tab.e[11] = { d_in[19], 128, 3328 };  // be4
    tab.e[12] = { d_in[10], 512, 3456 };  // Wc
    tab.e[13] = { d_in[11], 4,   3968 };  // bc
    float* b1f = pbuf + 0,   *g1f = pbuf + 256,  *be1f = pbuf + 512;
    float* b2f = pbuf + 768, *g2f = pbuf + 1280, *be2f = pbuf + 1792;
    float* b3f = pbuf + 2304,*g3f = pbuf + 2560, *be3f = pbuf + 2816;
    float* b4f = pbuf + 3072,*g4f = pbuf + 3200, *be4f = pbuf + 3328;
    float* Wcf = pbuf + 3456,*bcf = pbuf + 3968;

    int NB = (N + SCAN_B - 1) / SCAN_B;

    // ---- dtype probes ----
    detect_k<<<1, 256, 0, stream>>>(ei, E, (const u16*)x, flag);

    // ---- canonicalize (x + weights + params, one kernel) ----
    {
        WEnt e0 = { d_in[2], W1t, 512, 256, 0 };
        WEnt e1 = { d_in[4], W2t, 256, 512, 512 * 256 };
        WEnt e2 = { d_in[6], W3t, 512, 256, 512 * 256 + 256 * 512 };
        WEnt e3 = { d_in[8], W4t, 256, 128, 512 * 256 * 2 + 256 * 512 };
        int wtotal = 512 * 256 * 2 + 256 * 512 + 256 * 128;
        int gw = (wtotal + 255) / 256;
        megacvt_k<<<GX_CVT + gw + 14, 256, 0, stream>>>(
            x, xbf, (long)N * 512 / 4, e0, e1, e2, e3, wtotal, tab, pbuf, flag, gw);
    }

    // ---- CSR build (bucket-sorted) ----
    histA_k<<<NB_E, 256, 0, stream>>>(ei, flag, hist, counts, E, N, NB_E, NBUK, shiftv);
    scan1_k<<<NH, SCAN_B, 0, stream>>>(hist, histincl, bsum, flatlen);
    scan2_k<<<1, SCAN_B, 0, stream>>>(bsum, bscan, NH);
    scatC_k<<<NB_E, 256, 0, stream>>>(ei, flag, histincl, bscan, hist, ebuf, counts,
                                      E, N, NB_E, NBUK, shiftv);
    scan1_k<<<NB, SCAN_B, 0, stream>>>(counts, incl, bsum, N);
    scan2_k<<<1, SCAN_B, 0, stream>>>(bsum, bscan, NB);
    finCSR_k<<<NB, SCAN_B, 0, stream>>>(incl, bscan, counts, rowptr, cursor, dinv, N);
    scatD_k<<<(E + N + 255) / 256, 256, 0, stream>>>(ebuf, cursor, col, E, N);

    int gx = (N + 127) / 128;          // 391
    int ga = (N + 3) / 4;

    // ---- layer 1: xbf[N,512] @ W1 -> agg+LN+ELU -> h1[N,256] ----
    gemm128_k<<<gx * 2, 256, 0, stream>>>(xbf, W1t, xw, N, 512, 256, 2);
    agg_k<256><<<ga, 256, 0, stream>>>(xw, rowptr, col, dinv, b1f, g1f, be1f,
                                       h1, nullptr, nullptr, flag, nullptr, nullptr, N);
    // ---- layer 2 (agg BEFORE GEMM: agg(h1 @ W2) == agg(h1) @ W2) ----
    agg_k<256><<<ga, 256, 0, stream>>>(h1, rowptr, col, dinv, nullptr, nullptr, nullptr,
                                       xw, nullptr, nullptr, flag, nullptr, nullptr, N);
    gemm128_k<<<gx * 4, 256, 0, stream>>>(xw, W2t, h2, N, 256, 512, 4);
    ln_elu_k<<<ga, 256, 0, stream>>>(h2, b2f, g2f, be2f, N);
    // ---- layer 3: h2[N,512] @ W3 -> agg+LN+ELU + h1 -> h1[N,256] ----
    gemm128_k<<<gx * 2, 256, 0, stream>>>(h2, W3t, xw, N, 512, 256, 2);
    agg_k<256><<<ga, 256, 0, stream>>>(xw, rowptr, col, dinv, b3f, g3f, be3f,
                                       h1, h1, nullptr, flag, nullptr, nullptr, N);
    // ---- layer 4: h1[N,256] @ W4 -> agg -> out_conv/out_bn + fused classifier ----
    gemm128_k<<<gx * 1, 256, 0, stream>>>(h1, W4t, xw, N, 256, 128, 1);
    agg_k<128><<<ga, 256, 0, stream>>>(xw, rowptr, col, dinv, b4f, g4f, be4f,
                                       nullptr, nullptr, d_out, flag, Wcf, bcf, N);
}

// Round 5
// 965.661 us; speedup vs baseline: 1.0382x; 1.0051x over previous
//
#include <hip/hip_runtime.h>
#include <hip/hip_bf16.h>
#include <math.h>

typedef unsigned short u16;
typedef u16 us8 __attribute__((ext_vector_type(8)));
typedef u16 us4 __attribute__((ext_vector_type(4)));
typedef float f32x4 __attribute__((ext_vector_type(4)));
typedef float f32x8 __attribute__((ext_vector_type(8)));
typedef __bf16 bf8 __attribute__((ext_vector_type(8)));

#define SCAN_B 256
#define CH 8192   // edges per bucket-sort block

__device__ __forceinline__ float bf2f(u16 v) {
    unsigned u = ((unsigned)v) << 16;
    return __builtin_bit_cast(float, u);
}
__device__ __forceinline__ u16 f2bf(float f) {
    unsigned u = __builtin_bit_cast(unsigned, f);
    unsigned lsb = (u >> 16) & 1;
    u += 0x7fff + lsb;
    return (u16)(u >> 16);
}
__device__ __forceinline__ void fma8(f32x8& acc, float w, us8 v) {
#pragma unroll
    for (int j = 0; j < 8; j++) acc[j] += w * bf2f(v[j]);
}

// ---------------- runtime dtype probes ----------------
__global__ void detect_k(const int* __restrict__ ei, int E,
                         const u16* __restrict__ xraw, int* flag) {
    __shared__ int c_i32, c_f32;
    if (threadIdx.x == 0) { c_i32 = 0; c_f32 = 0; }
    __syncthreads();
    int ne = (E < 4096) ? E : 4096;
    for (int e = threadIdx.x; e < ne; e += blockDim.x)
        if (ei[2 * e + 1] != 0) c_i32 = 1;
    for (int k = threadIdx.x; k < 8192; k += blockDim.x) {
        u16 v = xraw[2 * k];
        int ex = (v >> 7) & 0xFF;
        if (ex >= 0xF0) atomicAdd(&c_f32, 1);
    }
    __syncthreads();
    if (threadIdx.x == 0) {
        flag[0] = (c_i32 == 0) ? 1 : 0;
        flag[1] = (c_f32 >= 4) ? 1 : 0;
    }
}

// ---------------- merged canonicalize: x + 4 weight transposes + params ----------
struct WEnt { const void* s; u16* dst; int K; int Nn; int base; };
struct PEnt { const void* s; int n; int off; };
struct PTab { PEnt e[14]; };

#define GX_CVT 4096

__global__ void megacvt_k(const void* __restrict__ xsrc, u16* __restrict__ xdst,
                          long nq, WEnt e0, WEnt e1, WEnt e2, WEnt e3, int wtotal,
                          PTab tab, float* __restrict__ pbuf,
                          const int* __restrict__ flag, int gw) {
    int f32m = flag[1];
    int bid = blockIdx.x;
    if (bid < GX_CVT) {                 // ---- x convert (grid-stride) ----
        long i0 = (long)bid * blockDim.x + threadIdx.x;
        long stride = (long)GX_CVT * blockDim.x;
        if (f32m) {
            const f32x4* s = (const f32x4*)xsrc;
            for (long i = i0; i < nq; i += stride) {
                f32x4 v = s[i];
                us4 o;
                #pragma unroll
                for (int j = 0; j < 4; j++) o[j] = f2bf(v[j]);
                ((us4*)xdst)[i] = o;
            }
        } else {
            const us4* s = (const us4*)xsrc;
            for (long i = i0; i < nq; i += stride) ((us4*)xdst)[i] = s[i];
        }
    } else if (bid < GX_CVT + gw) {     // ---- weight transpose+convert ----
        int t = (bid - GX_CVT) * blockDim.x + threadIdx.x;
        if (t >= wtotal) return;
        WEnt en = (t >= e3.base) ? e3 : ((t >= e2.base) ? e2 : ((t >= e1.base) ? e1 : e0));
        int li = t - en.base;
        int k = li / en.Nn, nn = li - k * en.Nn;
        u16 b;
        if (f32m) b = f2bf(((const float*)en.s)[li]);
        else      b = ((const u16*)en.s)[li];
        en.dst[nn * en.K + k] = b;
    } else {                            // ---- small params -> f32 ----
        PEnt en = tab.e[bid - GX_CVT - gw];
        for (int i = threadIdx.x; i < en.n; i += blockDim.x) {
            float v = f32m ? ((const float*)en.s)[i] : bf2f(((const u16*)en.s)[i]);
            pbuf[en.off + i] = v;
        }
    }
}

// ---------------- CSR build (bucket-sorted, low write-amplification) ----------------
// Pass A: per-block bucket histogram (bucket = dst >> shiftv) + counts init fused
__global__ void histA_k(const int* __restrict__ ei, const int* __restrict__ flag,
                        int* __restrict__ hist, int* __restrict__ counts,
                        int E, int n, int NB, int NBUK, int shiftv) {
    __shared__ int lh[256];
    int blk = blockIdx.x;
    int gi = blk * 256 + threadIdx.x;   // NB*256 >= n guaranteed (NB>=196)
    if (gi < n) counts[gi] = 1;         // self-loop init (consumed later by scatC)
    for (int b = threadIdx.x; b < NBUK; b += 256) lh[b] = 0;
    __syncthreads();
    int e0 = blk * CH;
    int e1 = min(e0 + CH, E);
    int i64 = flag[0];
    for (int e = e0 + threadIdx.x; e < e1; e += 256) {
        int d;
        if (i64) d = (int)((const long long*)ei)[(size_t)E + e];
        else     d = ei[(size_t)E + e];
        int b = ((unsigned)d < (unsigned)n) ? min(d >> shiftv, NBUK - 1) : (NBUK - 1);
        atomicAdd(&lh[b], 1);
    }
    __syncthreads();
    for (int b = threadIdx.x; b < NBUK; b += 256) hist[b * NB + blk] = lh[b];
}

// generic block-scan (also reused for node-degree scan)
__global__ void scan1_k(const int* __restrict__ counts, int* incl, int* bsum, int n) {
    __shared__ int tmp[SCAN_B];
    int t = threadIdx.x;
    int i = blockIdx.x * SCAN_B + t;
    int v = (i < n) ? counts[i] : 0;
    tmp[t] = v;
    __syncthreads();
    for (int o = 1; o < SCAN_B; o <<= 1) {
        int x = 0;
        if (t >= o) x = tmp[t - o];
        __syncthreads();
        if (t >= o) tmp[t] += x;
        __syncthreads();
    }
    if (i < n) incl[i] = tmp[t];
    if (t == SCAN_B - 1) bsum[blockIdx.x] = tmp[t];
}

__global__ void scan2_k(const int* __restrict__ bsum, int* bscan, int nb) {
    __shared__ int tmp[SCAN_B];
    int t = threadIdx.x;
    tmp[t] = (t < nb) ? bsum[t] : 0;
    __syncthreads();
    for (int o = 1; o < SCAN_B; o <<= 1) {
        int x = 0;
        if (t >= o) x = tmp[t - o];
        __syncthreads();
        if (t >= o) tmp[t] += x;
        __syncthreads();
    }
    bscan[t] = tmp[t];
}

// Pass C: bucket-scatter packed (src,dst) pairs via LDS cursors.
// Cursor computed inline (exclA fused): ofs(fi) = histincl[fi] + bscan_prev - hist[fi].
__global__ void scatC_k(const int* __restrict__ ei, const int* __restrict__ flag,
                        const int* __restrict__ histincl, const int* __restrict__ bscan,
                        const int* __restrict__ hist, long long* __restrict__ ebuf,
                        int* __restrict__ counts,
                        int E, int n, int NB, int NBUK, int shiftv) {
    __shared__ int cur[256];
    int blk = blockIdx.x;
    for (int b = threadIdx.x; b < NBUK; b += 256) {
        int fi = b * NB + blk;
        int boff = (fi >= 256) ? bscan[(fi >> 8) - 1] : 0;
        cur[b] = histincl[fi] + boff - hist[fi];
    }
    __syncthreads();
    int e0 = blk * CH;
    int e1 = min(e0 + CH, E);
    int i64 = flag[0];
    for (int e = e0 + threadIdx.x; e < e1; e += 256) {
        int s, d;
        if (i64) {
            const long long* e64 = (const long long*)ei;
            s = (int)e64[e]; d = (int)e64[(size_t)E + e];
        } else {
            s = ei[e]; d = ei[(size_t)E + e];
        }
        int b = ((unsigned)d < (unsigned)n) ? min(d >> shiftv, NBUK - 1) : (NBUK - 1);
        int pos = atomicAdd(&cur[b], 1);
        ebuf[pos] = ((long long)(unsigned)d << 32) | (unsigned)s;
        if ((unsigned)d < (unsigned)n) atomicAdd(&counts[d], 1);
    }
}

// fused CSR epilogue: rowptr + cursor + dinv in one pass (grid = NB x SCAN_B)
__global__ void finCSR_k(const int* __restrict__ incl, const int* __restrict__ bscan,
                         const int* __restrict__ counts, int* __restrict__ rowptr,
                         int* __restrict__ cursor, float* __restrict__ dinv, int n) {
    int i = blockIdx.x * SCAN_B + threadIdx.x;
    if (i < n) {
        int boff = (blockIdx.x > 0) ? bscan[blockIdx.x - 1] : 0;
        int rp_end = incl[i] + boff;         // inclusive scan = row end
        rowptr[i + 1] = rp_end;
        if (i == 0) rowptr[0] = 0;
        cursor[i] = rp_end - counts[i];      // row start, no read-after-write hazard
        dinv[i] = rsqrtf((float)counts[i]);
    }
}

// Pass D: final CSR scatter from bucket-sorted pairs (dense col-window writes)
__global__ void scatD_k(const long long* __restrict__ ebuf, int* cursor,
                        int* __restrict__ col, int E, int n) {
    int e = blockIdx.x * blockDim.x + threadIdx.x;
    if (e < E) {
        long long pr = ebuf[e];
        int d = (int)(pr >> 32);
        int s = (int)(pr & 0xffffffffLL);
        if ((unsigned)s < (unsigned)n && (unsigned)d < (unsigned)n) {
            int pos = atomicAdd(&cursor[d], 1);
            col[pos] = s;
        }
    } else if (e < E + n) {
        int i = e - E;
        int pos = atomicAdd(&cursor[i], 1);
        col[pos] = i;
    }
}

// ---------------- bf16 MFMA GEMM, 2-phase double-buffered ----------------------------
// C[M,Nn] = A[M,K] * Bt[Nn,K]^T. 128x128 tile, BK=32, 4 waves x (4x4 16x16 frags).
// T3-minimum schedule [catalog §5.5, m230/m248]: prologue-stage buf0, then per K-step
// {issue stage(buf^1) -> ds_read+MFMA on buf -> ONE __syncthreads}. The barrier's
// vmcnt drain overlaps next tile's HBM latency with current tile's MFMA — critical
// at this problem's 1.5-6 blocks/CU where m97's implicit wave-overlap is absent.
// 1D grid with XCD-aware bijective remap [T1, m204]: ny blocks sharing one 128-row
// A-panel land on the SAME XCD -> A-panel L2-resident.
typedef __attribute__((address_space(1))) const void gas_v;
typedef __attribute__((address_space(3))) void las_v;

__global__ __launch_bounds__(256) void gemm128_k(
    const u16* __restrict__ A, const u16* __restrict__ Bt,
    u16* __restrict__ C, int M, int K, int Nn, int nyv) {
    int nx = (M + 127) >> 7;
    int nfull = nx & ~7;
    int cutoff = nfull * nyv;
    int b = blockIdx.x;
    int bx, by;
    if (b < cutoff) {
        int k = b & 7;            // XCD id (blockIdx % 8 round-robin [m09])
        int q = b >> 3;
        by = q % nyv;
        bx = (q / nyv) * 8 + k;   // all ny blocks of panel bx share XCD k
    } else {
        int r = b - cutoff;
        bx = nfull + r / nyv;
        by = r % nyv;
    }

    __shared__ u16 As[2][128 * 32];
    __shared__ u16 Bs[2][128 * 32];
    int tid = threadIdx.x;
    int wave = tid >> 6;
    int lane = tid & 63;
    int wr = (wave >> 1) * 64;   // wave row offset in tile
    int wc = (wave & 1) * 64;    // wave col offset in tile
    long row0 = (long)bx * 128;
    int col0 = by * 128;
    int lr = lane >> 2;          // 0..15 : row within 16-row staging chunk
    int lc = lane & 3;           // 0..3  : 16B column chunk
    int m = lane & 15;
    int q = lane >> 4;

    // per-thread staging addresses (row fixed across K, only k0 advances)
    long ar0 = row0 + (wave + 0) * 16 + lr;
    long ar1 = row0 + (wave + 4) * 16 + lr;
    if (ar0 > (long)M - 1) ar0 = (long)M - 1;  // clamp: garbage feeds masked rows only
    if (ar1 > (long)M - 1) ar1 = (long)M - 1;
    const u16* gA0 = A + ar0 * K + lc * 8;
    const u16* gA1 = A + ar1 * K + lc * 8;
    const u16* gB0 = Bt + (size_t)(col0 + (wave + 0) * 16 + lr) * K + lc * 8;
    const u16* gB1 = Bt + (size_t)(col0 + (wave + 4) * 16 + lr) * K + lc * 8;
    int lds0 = (wave + 0) * 512;   // u16 index of chunk base in LDS tile
    int lds1 = (wave + 4) * 512;

    f32x4 acc[4][4];
    #pragma unroll
    for (int i = 0; i < 4; i++)
        #pragma unroll
        for (int j = 0; j < 4; j++) acc[i][j] = (f32x4){0.f, 0.f, 0.f, 0.f};

    // prologue: stage K-tile 0 into buf 0
    __builtin_amdgcn_global_load_lds((gas_v*)(gA0), (las_v*)&As[0][lds0], 16, 0, 0);
    __builtin_amdgcn_global_load_lds((gas_v*)(gA1), (las_v*)&As[0][lds1], 16, 0, 0);
    __builtin_amdgcn_global_load_lds((gas_v*)(gB0), (las_v*)&Bs[0][lds0], 16, 0, 0);
    __builtin_amdgcn_global_load_lds((gas_v*)(gB1), (las_v*)&Bs[0][lds1], 16, 0, 0);
    __syncthreads();   // drains vmcnt: tile 0 resident

    int cur = 0;
    for (int k0 = 0; k0 < K; k0 += 32) {
        // issue next K-tile's loads into the other buffer (overlaps with MFMA below)
        if (k0 + 32 < K) {
            int nb = cur ^ 1;
            int ko = k0 + 32;
            __builtin_amdgcn_global_load_lds((gas_v*)(gA0 + ko), (las_v*)&As[nb][lds0], 16, 0, 0);
            __builtin_amdgcn_global_load_lds((gas_v*)(gA1 + ko), (las_v*)&As[nb][lds1], 16, 0, 0);
            __builtin_amdgcn_global_load_lds((gas_v*)(gB0 + ko), (las_v*)&Bs[nb][lds0], 16, 0, 0);
            __builtin_amdgcn_global_load_lds((gas_v*)(gB1 + ko), (las_v*)&Bs[nb][lds1], 16, 0, 0);
        }

        us8 av[4], bv[4];
        #pragma unroll
        for (int i = 0; i < 4; i++) {
            av[i] = *(const us8*)&As[cur][(wr + i * 16 + m) * 32 + q * 8];
            bv[i] = *(const us8*)&Bs[cur][(wc + i * 16 + m) * 32 + q * 8];
        }
        #pragma unroll
        for (int i = 0; i < 4; i++) {
            bf8 fa = __builtin_bit_cast(bf8, av[i]);
            #pragma unroll
            for (int j = 0; j < 4; j++) {
                bf8 fb = __builtin_bit_cast(bf8, bv[j]);
                acc[i][j] = __builtin_amdgcn_mfma_f32_16x16x32_bf16(fa, fb, acc[i][j], 0, 0, 0);
            }
        }
        __syncthreads();   // drains vmcnt (next tile ready) + guards buf reuse
        cur ^= 1;
    }

    // C/D layout: col = lane&15, row = (lane>>4)*4 + r  [measured m89]
    #pragma unroll
    for (int i = 0; i < 4; i++) {
        #pragma unroll
        for (int r = 0; r < 4; r++) {
            long row = row0 + wr + i * 16 + q * 4 + r;
            if (row < M) {
                #pragma unroll
                for (int j = 0; j < 4; j++)
                    C[row * Nn + col0 + wc + j * 16 + m] = f2bf(acc[i][j][r]);
            }
        }
    }
}

// ---------------- wave-per-node aggregate [+ bias + LN + ELU (+resid) (+classifier)] ---
// F templated: s*F becomes shift, rowt/Gw constexpr (VALU addressing cut).
// 2-deep unroll: agg is L2-miss-throughput-bound (dur = FETCH/3.2TB/s);
// unroll-4 measured -8% (r1), deeper MLP can't help a full miss queue.
template <int F>
__global__ __launch_bounds__(256) void agg_k(
    const u16* __restrict__ in, const int* __restrict__ rowptr,
    const int* __restrict__ col, const float* __restrict__ dinv,
    const float* __restrict__ bias, const float* __restrict__ gamma,
    const float* __restrict__ beta, u16* __restrict__ out_h,
    const u16* __restrict__ resid, void* __restrict__ final_base,
    const int* __restrict__ flag, const float* __restrict__ Wcf,
    const float* __restrict__ bcf, int nN) {
    int wv = threadIdx.x >> 6;
    int lane = threadIdx.x & 63;
    int i = blockIdx.x * 4 + wv;
    if (i >= nN) return;

    constexpr int rowt = F >> 3;          // 32 (F=256) or 16 (F=128)
    constexpr int Gw = 64 / rowt;         // 2 or 4 edge groups per wave
    int g = lane / rowt;
    int f0 = (lane & (rowt - 1)) << 3;

    int beg = rowptr[i], end = rowptr[i + 1];
    f32x8 acc = {0, 0, 0, 0, 0, 0, 0, 0}, acc2 = acc;
    int e = beg + g;
    for (; e + Gw < end; e += 2 * Gw) {
        int s0 = col[e], s1 = col[e + Gw];
        s0 = ((unsigned)s0 < (unsigned)nN) ? s0 : 0;
        s1 = ((unsigned)s1 < (unsigned)nN) ? s1 : 0;
        float w0 = dinv[s0], w1 = dinv[s1];
        us8 v0 = *(const us8*)(in + (unsigned)(s0 * F) + f0);
        us8 v1 = *(const us8*)(in + (unsigned)(s1 * F) + f0);
        fma8(acc, w0, v0);
        fma8(acc2, w1, v1);
    }
    if (e < end) {
        int s = col[e];
        s = ((unsigned)s < (unsigned)nN) ? s : 0;
        us8 v = *(const us8*)(in + (unsigned)(s * F) + f0);
        fma8(acc, dinv[s], v);
    }
    #pragma unroll
    for (int j = 0; j < 8; j++) acc[j] += acc2[j];

    #pragma unroll
    for (int o = 32; o >= rowt; o >>= 1) {
        #pragma unroll
        for (int j = 0; j < 8; j++) acc[j] += __shfl_down(acc[j], o);
    }
    bool active = lane < rowt;
    float di = dinv[i];

    if (!bias) {  // plain mode (layer-2 pre-aggregate)
        if (active) {
            us8 o8;
            #pragma unroll
            for (int j = 0; j < 8; j++) o8[j] = f2bf(di * acc[j]);
            *(us8*)(out_h + (unsigned)(i * F) + f0) = o8;
        }
        return;
    }

    f32x8 accv = {0, 0, 0, 0, 0, 0, 0, 0};
    if (active) {
        #pragma unroll
        for (int j = 0; j < 8; j++) accv[j] = di * acc[j] + bias[f0 + j];
    }
    int f32m = final_base ? flag[1] : 0;
    if (final_base && active) {
        size_t conv_idx = (size_t)nN * 4 + (size_t)i * F + f0;
        if (f32m) {
            #pragma unroll
            for (int j = 0; j < 8; j++) ((float*)final_base)[conv_idx + j] = accv[j];
        } else {
            us8 o8;
            #pragma unroll
            for (int j = 0; j < 8; j++) o8[j] = f2bf(accv[j]);
            *(us8*)((u16*)final_base + conv_idx) = o8;
        }
    }

    float p1 = 0.f, p2 = 0.f;
    #pragma unroll
    for (int j = 0; j < 8; j++) { p1 += accv[j]; p2 += accv[j] * accv[j]; }
    #pragma unroll
    for (int o = rowt >> 1; o >= 1; o >>= 1) {
        p1 += __shfl_xor(p1, o);
        p2 += __shfl_xor(p2, o);
    }
    constexpr float invF = 1.0f / (float)F;
    float mu = p1 * invF;
    float var = fmaxf(p2 * invF - mu * mu, 0.f);
    float rstd = rsqrtf(var + 1e-5f);

    f32x8 h8 = {0, 0, 0, 0, 0, 0, 0, 0};
    if (active) {
        f32x8 y8;
        #pragma unroll
        for (int j = 0; j < 8; j++)
            y8[j] = (accv[j] - mu) * rstd * gamma[f0 + j] + beta[f0 + j];
        if (final_base) {
            size_t bn_idx = (size_t)nN * 4 + (size_t)nN * F + (size_t)i * F + f0;
            if (f32m) {
                #pragma unroll
                for (int j = 0; j < 8; j++) ((float*)final_base)[bn_idx + j] = y8[j];
            } else {
                us8 o8;
                #pragma unroll
                for (int j = 0; j < 8; j++) o8[j] = f2bf(y8[j]);
                *(us8*)((u16*)final_base + bn_idx) = o8;
            }
        }
        #pragma unroll
        for (int j = 0; j < 8; j++) h8[j] = (y8[j] > 0.f) ? y8[j] : expm1f(y8[j]);
        if (resid) {
            us8 r8 = *(const us8*)(resid + (unsigned)(i * F) + f0);
            #pragma unroll
            for (int j = 0; j < 8; j++) h8[j] += bf2f(r8[j]);
        }
        if (out_h) {
            us8 o8;
            #pragma unroll
            for (int j = 0; j < 8; j++) o8[j] = f2bf(h8[j]);
            *(us8*)(out_h + (unsigned)(i * F) + f0) = o8;
        }
    }

    if (Wcf) {
        float s0 = 0.f, s1 = 0.f, s2 = 0.f, s3 = 0.f;
        if (active) {
            #pragma unroll
            for (int j = 0; j < 8; j++) {
                const float* wr = Wcf + (f0 + j) * 4;
                s0 += h8[j] * wr[0];
                s1 += h8[j] * wr[1];
                s2 += h8[j] * wr[2];
                s3 += h8[j] * wr[3];
            }
        }
        #pragma unroll
        for (int o = rowt >> 1; o >= 1; o >>= 1) {
            s0 += __shfl_xor(s0, o);
            s1 += __shfl_xor(s1, o);
            s2 += __shfl_xor(s2, o);
            s3 += __shfl_xor(s3, o);
        }
        if (lane == 0) {
            size_t lidx = (size_t)i * 4;
            if (f32m) {
                ((float*)final_base)[lidx + 0] = s0 + bcf[0];
                ((float*)final_base)[lidx + 1] = s1 + bcf[1];
                ((float*)final_base)[lidx + 2] = s2 + bcf[2];
                ((float*)final_base)[lidx + 3] = s3 + bcf[3];
            } else {
                ((u16*)final_base)[lidx + 0] = f2bf(s0 + bcf[0]);
                ((u16*)final_base)[lidx + 1] = f2bf(s1 + bcf[1]);
                ((u16*)final_base)[lidx + 2] = f2bf(s2 + bcf[2]);
                ((u16*)final_base)[lidx + 3] = f2bf(s3 + bcf[3]);
            }
        }
    }
}

// ---------------- bias + LayerNorm + ELU in place, wave-per-node, F=512 ----------
__global__ __launch_bounds__(256) void ln_elu_k(u16* __restrict__ h,
                                                const float* __restrict__ bias,
                                                const float* __restrict__ gamma,
                                                const float* __restrict__ beta, int nN) {
    int wv = threadIdx.x >> 6;
    int lane = threadIdx.x & 63;
    int i = blockIdx.x * 4 + wv;
    if (i >= nN) return;
    int f0 = lane * 8;                       // 64 lanes x 8 = 512 features
    size_t base = (size_t)i * 512 + f0;
    us8 v8 = *(const us8*)(h + base);
    f32x8 v;
    #pragma unroll
    for (int j = 0; j < 8; j++) v[j] = bf2f(v8[j]) + bias[f0 + j];
    float p1 = 0.f, p2 = 0.f;
    #pragma unroll
    for (int j = 0; j < 8; j++) { p1 += v[j]; p2 += v[j] * v[j]; }
    #pragma unroll
    for (int o = 32; o >= 1; o >>= 1) {
        p1 += __shfl_xor(p1, o);
        p2 += __shfl_xor(p2, o);
    }
    const float invF = 1.0f / 512.0f;
    float mu = p1 * invF;
    float var = fmaxf(p2 * invF - mu * mu, 0.f);
    float rstd = rsqrtf(var + 1e-5f);
    us8 o8;
    #pragma unroll
    for (int j = 0; j < 8; j++) {
        float y = (v[j] - mu) * rstd * gamma[f0 + j] + beta[f0 + j];
        y = (y > 0.f) ? y : expm1f(y);
        o8[j] = f2bf(y);
    }
    *(us8*)(h + base) = o8;
}

// ---------------- ws-too-small marker ----------------
__global__ void marker_k(float* out) {
    if (threadIdx.x == 0 && blockIdx.x == 0) {
        out[0] = 31337.0f; out[1] = 31337.0f;
    }
}

extern "C" void kernel_launch(void* const* d_in, const int* in_sizes, int n_in,
                              void* d_out, int out_size, void* d_ws, size_t ws_size,
                              hipStream_t stream) {
    const int N = in_sizes[0] / 512;   // 50000
    const int E = in_sizes[1] / 2;     // 1600000

    const void* x  = d_in[0];
    const int* ei  = (const int*)d_in[1];

    // ---- workspace carve ----
    char* p = (char*)d_ws;
    auto alloc = [&](size_t bytes) -> void* {
        void* r = (void*)p;
        p += (bytes + 255) & ~(size_t)255;
        return r;
    };
    int*   flag   = (int*)alloc(256);
    int*   counts = (int*)alloc((size_t)N * 4);
    int*   rowptr = (int*)alloc((size_t)(N + 1) * 4);
    int*   cursor = (int*)alloc((size_t)N * 4);
    int*   incl   = (int*)alloc((size_t)N * 4);
    int*   bsum   = (int*)alloc(256 * 4);
    int*   bscan  = (int*)alloc(256 * 4);
    float* dinv   = (float*)alloc((size_t)N * 4);
    int*   col    = (int*)alloc((size_t)(E + N) * 4);
    float* pbuf   = (float*)alloc(4096 * 4);
    u16* W1t = (u16*)alloc((size_t)512 * 256 * 2);
    u16* W2t = (u16*)alloc((size_t)256 * 512 * 2);
    u16* W3t = (u16*)alloc((size_t)512 * 256 * 2);
    u16* W4t = (u16*)alloc((size_t)256 * 128 * 2);
    u16* bigA = (u16*)alloc((size_t)N * 512 * 2);  // xbf -> h2
    u16* xw   = (u16*)alloc((size_t)N * 256 * 2);  // ebuf (CSR build) -> GEMM scratch
    u16* h1   = (u16*)alloc((size_t)N * 256 * 2);  // hist arrays (CSR build) -> h1

    size_t needed = (size_t)(p - (char*)d_ws);
    if (needed > ws_size) {
        marker_k<<<1, 64, 0, stream>>>((float*)d_out);
        return;
    }

    u16* xbf = bigA;
    u16* h2  = bigA;  // [N,512], alive after xbf dead

    // bucket-sort params (dead buffers aliased; all CSR work precedes their next use)
    int shiftv = 8;
    while (((N - 1) >> shiftv) > 255) shiftv++;
    int NBUK = ((N - 1) >> shiftv) + 1;            // 196 for N=50000
    int NB_E = (E + CH - 1) / CH;                  // 196 for E=1.6M
    int flatlen = NBUK * NB_E;                     // ~38k
    int NH = (flatlen + 255) / 256;                // <=256 required
    long long* ebuf = (long long*)xw;              // E*8 B <= N*256*2 B
    int* hist     = (int*)h1;
    int* histincl = hist + flatlen;

    PTab tab;
    tab.e[0]  = { d_in[3],  256, 0    };  // b1
    tab.e[1]  = { d_in[12], 256, 256  };  // g1
    tab.e[2]  = { d_in[13], 256, 512  };  // be1
    tab.e[3]  = { d_in[5],  512, 768  };  // b2
    tab.e[4]  = { d_in[14], 512, 1280 };  // g2
    tab.e[5]  = { d_in[15], 512, 1792 };  // be2
    tab.e[6]  = { d_in[7],  256, 2304 };  // b3
    tab.e[7]  = { d_in[16], 256, 2560 };  // g3
    tab.e[8]  = { d_in[17], 256, 2816 };  // be3
    tab.e[9]  = { d_in[9],  128, 3072 };  // b4
    tab.e[10] = { d_in[18], 128, 3200 };  // g4
    tab.e[11] = { d_in[19], 128, 3328 };  // be4
    tab.e[12] = { d_in[10], 512, 3456 };  // Wc
    tab.e[13] = { d_in[11], 4,   3968 };  // bc
    float* b1f = pbuf + 0,   *g1f = pbuf + 256,  *be1f = pbuf + 512;
    float* b2f = pbuf + 768, *g2f = pbuf + 1280, *be2f = pbuf + 1792;
    float* b3f = pbuf + 2304,*g3f = pbuf + 2560, *be3f = pbuf + 2816;
    float* b4f = pbuf + 3072,*g4f = pbuf + 3200, *be4f = pbuf + 3328;
    float* Wcf = pbuf + 3456,*bcf = pbuf + 3968;

    int NB = (N + SCAN_B - 1) / SCAN_B;

    // ---- dtype probes ----
    detect_k<<<1, 256, 0, stream>>>(ei, E, (const u16*)x, flag);

    // ---- canonicalize (x + weights + params, one kernel) ----
    {
        WEnt e0 = { d_in[2], W1t, 512, 256, 0 };
        WEnt e1 = { d_in[4], W2t, 256, 512, 512 * 256 };
        WEnt e2 = { d_in[6], W3t, 512, 256, 512 * 256 + 256 * 512 };
        WEnt e3 = { d_in[8], W4t, 256, 128, 512 * 256 * 2 + 256 * 512 };
        int wtotal = 512 * 256 * 2 + 256 * 512 + 256 * 128;
        int gw = (wtotal + 255) / 256;
        megacvt_k<<<GX_CVT + gw + 14, 256, 0, stream>>>(
            x, xbf, (long)N * 512 / 4, e0, e1, e2, e3, wtotal, tab, pbuf, flag, gw);
    }

    // ---- CSR build (bucket-sorted) ----
    histA_k<<<NB_E, 256, 0, stream>>>(ei, flag, hist, counts, E, N, NB_E, NBUK, shiftv);
    scan1_k<<<NH, SCAN_B, 0, stream>>>(hist, histincl, bsum, flatlen);
    scan2_k<<<1, SCAN_B, 0, stream>>>(bsum, bscan, NH);
    scatC_k<<<NB_E, 256, 0, stream>>>(ei, flag, histincl, bscan, hist, ebuf, counts,
                                      E, N, NB_E, NBUK, shiftv);
    scan1_k<<<NB, SCAN_B, 0, stream>>>(counts, incl, bsum, N);
    scan2_k<<<1, SCAN_B, 0, stream>>>(bsum, bscan, NB);
    finCSR_k<<<NB, SCAN_B, 0, stream>>>(incl, bscan, counts, rowptr, cursor, dinv, N);
    scatD_k<<<(E + N + 255) / 256, 256, 0, stream>>>(ebuf, cursor, col, E, N);

    int gx = (N + 127) / 128;          // 391
    int ga = (N + 3) / 4;

    // ---- layer 1: xbf[N,512] @ W1 -> agg+LN+ELU -> h1[N,256] ----
    gemm128_k<<<gx * 2, 256, 0, stream>>>(xbf, W1t, xw, N, 512, 256, 2);
    agg_k<256><<<ga, 256, 0, stream>>>(xw, rowptr, col, dinv, b1f, g1f, be1f,
                                       h1, nullptr, nullptr, flag, nullptr, nullptr, N);
    // ---- layer 2 (agg BEFORE GEMM: agg(h1 @ W2) == agg(h1) @ W2) ----
    agg_k<256><<<ga, 256, 0, stream>>>(h1, rowptr, col, dinv, nullptr, nullptr, nullptr,
                                       xw, nullptr, nullptr, flag, nullptr, nullptr, N);
    gemm128_k<<<gx * 4, 256, 0, stream>>>(xw, W2t, h2, N, 256, 512, 4);
    ln_elu_k<<<ga, 256, 0, stream>>>(h2, b2f, g2f, be2f, N);
    // ---- layer 3: h2[N,512] @ W3 -> agg+LN+ELU + h1 -> h1[N,256] ----
    gemm128_k<<<gx * 2, 256, 0, stream>>>(h2, W3t, xw, N, 512, 256, 2);
    agg_k<256><<<ga, 256, 0, stream>>>(xw, rowptr, col, dinv, b3f, g3f, be3f,
                                       h1, h1, nullptr, flag, nullptr, nullptr, N);
    // ---- layer 4: h1[N,256] @ W4 -> agg -> out_conv/out_bn + fused classifier ----
    gemm128_k<<<gx * 1, 256, 0, stream>>>(h1, W4t, xw, N, 256, 128, 1);
    agg_k<128><<<ga, 256, 0, stream>>>(xw, rowptr, col, dinv, b4f, g4f, be4f,
                                       nullptr, nullptr, d_out, flag, Wcf, bcf, N);
}

// Round 7
// 898.741 us; speedup vs baseline: 1.1155x; 1.0745x over previous
//
#include <hip/hip_runtime.h>
#include <hip/hip_bf16.h>
#include <math.h>

typedef unsigned short u16;
typedef u16 us8 __attribute__((ext_vector_type(8)));
typedef u16 us4 __attribute__((ext_vector_type(4)));
typedef float f32x4 __attribute__((ext_vector_type(4)));
typedef float f32x8 __attribute__((ext_vector_type(8)));
typedef __bf16 bf8 __attribute__((ext_vector_type(8)));

#define SCAN_B 256
#define CH 8192   // edges per bucket-sort block

__device__ __forceinline__ float bf2f(u16 v) {
    unsigned u = ((unsigned)v) << 16;
    return __builtin_bit_cast(float, u);
}
__device__ __forceinline__ u16 f2bf(float f) {
    unsigned u = __builtin_bit_cast(unsigned, f);
    unsigned lsb = (u >> 16) & 1;
    u += 0x7fff + lsb;
    return (u16)(u >> 16);
}
__device__ __forceinline__ void fma8(f32x8& acc, float w, us8 v) {
#pragma unroll
    for (int j = 0; j < 8; j++) acc[j] += w * bf2f(v[j]);
}

// ---------------- runtime dtype probes ----------------
__global__ void detect_k(const int* __restrict__ ei, int E,
                         const u16* __restrict__ xraw, int* flag) {
    __shared__ int c_i32, c_f32;
    if (threadIdx.x == 0) { c_i32 = 0; c_f32 = 0; }
    __syncthreads();
    int ne = (E < 4096) ? E : 4096;
    for (int e = threadIdx.x; e < ne; e += blockDim.x)
        if (ei[2 * e + 1] != 0) c_i32 = 1;
    for (int k = threadIdx.x; k < 8192; k += blockDim.x) {
        u16 v = xraw[2 * k];
        int ex = (v >> 7) & 0xFF;
        if (ex >= 0xF0) atomicAdd(&c_f32, 1);
    }
    __syncthreads();
    if (threadIdx.x == 0) {
        flag[0] = (c_i32 == 0) ? 1 : 0;
        flag[1] = (c_f32 >= 4) ? 1 : 0;
    }
}

// ---------------- merged canonicalize: x + 4 weight transposes + params ----------
struct WEnt { const void* s; u16* dst; int K; int Nn; int base; };
struct PEnt { const void* s; int n; int off; };
struct PTab { PEnt e[14]; };

#define GX_CVT 4096

__global__ void megacvt_k(const void* __restrict__ xsrc, u16* __restrict__ xdst,
                          long nq, WEnt e0, WEnt e1, WEnt e2, WEnt e3, int wtotal,
                          PTab tab, float* __restrict__ pbuf,
                          const int* __restrict__ flag, int gw) {
    int f32m = flag[1];
    int bid = blockIdx.x;
    if (bid < GX_CVT) {                 // ---- x convert (grid-stride) ----
        long i0 = (long)bid * blockDim.x + threadIdx.x;
        long stride = (long)GX_CVT * blockDim.x;
        if (f32m) {
            const f32x4* s = (const f32x4*)xsrc;
            for (long i = i0; i < nq; i += stride) {
                f32x4 v = s[i];
                us4 o;
                #pragma unroll
                for (int j = 0; j < 4; j++) o[j] = f2bf(v[j]);
                ((us4*)xdst)[i] = o;
            }
        } else {
            const us4* s = (const us4*)xsrc;
            for (long i = i0; i < nq; i += stride) ((us4*)xdst)[i] = s[i];
        }
    } else if (bid < GX_CVT + gw) {     // ---- weight transpose+convert ----
        int t = (bid - GX_CVT) * blockDim.x + threadIdx.x;
        if (t >= wtotal) return;
        WEnt en = (t >= e3.base) ? e3 : ((t >= e2.base) ? e2 : ((t >= e1.base) ? e1 : e0));
        int li = t - en.base;
        int k = li / en.Nn, nn = li - k * en.Nn;
        u16 b;
        if (f32m) b = f2bf(((const float*)en.s)[li]);
        else      b = ((const u16*)en.s)[li];
        en.dst[nn * en.K + k] = b;
    } else {                            // ---- small params -> f32 ----
        PEnt en = tab.e[bid - GX_CVT - gw];
        for (int i = threadIdx.x; i < en.n; i += blockDim.x) {
            float v = f32m ? ((const float*)en.s)[i] : bf2f(((const u16*)en.s)[i]);
            pbuf[en.off + i] = v;
        }
    }
}

// ---------------- CSR build (bucket-sorted; ZERO global atomics) -------------------
// Pass A: per-block bucket histogram (bucket = dst >> shiftv)
__global__ void histA_k(const int* __restrict__ ei, const int* __restrict__ flag,
                        int* __restrict__ hist,
                        int E, int n, int NB, int NBUK, int shiftv) {
    __shared__ int lh[256];
    int blk = blockIdx.x;
    for (int b = threadIdx.x; b < NBUK; b += 256) lh[b] = 0;
    __syncthreads();
    int e0 = blk * CH;
    int e1 = min(e0 + CH, E);
    int i64 = flag[0];
    for (int e = e0 + threadIdx.x; e < e1; e += 256) {
        int d;
        if (i64) d = (int)((const long long*)ei)[(size_t)E + e];
        else     d = ei[(size_t)E + e];
        int b = ((unsigned)d < (unsigned)n) ? min(d >> shiftv, NBUK - 1) : (NBUK - 1);
        atomicAdd(&lh[b], 1);
    }
    __syncthreads();
    for (int b = threadIdx.x; b < NBUK; b += 256) hist[b * NB + blk] = lh[b];
}

// generic block-scan (also reused for node-degree scan)
__global__ void scan1_k(const int* __restrict__ counts, int* incl, int* bsum, int n) {
    __shared__ int tmp[SCAN_B];
    int t = threadIdx.x;
    int i = blockIdx.x * SCAN_B + t;
    int v = (i < n) ? counts[i] : 0;
    tmp[t] = v;
    __syncthreads();
    for (int o = 1; o < SCAN_B; o <<= 1) {
        int x = 0;
        if (t >= o) x = tmp[t - o];
        __syncthreads();
        if (t >= o) tmp[t] += x;
        __syncthreads();
    }
    if (i < n) incl[i] = tmp[t];
    if (t == SCAN_B - 1) bsum[blockIdx.x] = tmp[t];
}

__global__ void scan2_k(const int* __restrict__ bsum, int* bscan, int nb) {
    __shared__ int tmp[SCAN_B];
    int t = threadIdx.x;
    tmp[t] = (t < nb) ? bsum[t] : 0;
    __syncthreads();
    for (int o = 1; o < SCAN_B; o <<= 1) {
        int x = 0;
        if (t >= o) x = tmp[t - o];
        __syncthreads();
        if (t >= o) tmp[t] += x;
        __syncthreads();
    }
    bscan[t] = tmp[t];
}

// Pass C: bucket-scatter packed (src,dst) pairs via LDS cursors.
// Cursor computed inline: ofs(fi) = histincl[fi] + bscan_prev - hist[fi].
__global__ void scatC_k(const int* __restrict__ ei, const int* __restrict__ flag,
                        const int* __restrict__ histincl, const int* __restrict__ bscan,
                        const int* __restrict__ hist, long long* __restrict__ ebuf,
                        int E, int n, int NB, int NBUK, int shiftv) {
    __shared__ int cur[256];
    int blk = blockIdx.x;
    for (int b = threadIdx.x; b < NBUK; b += 256) {
        int fi = b * NB + blk;
        int boff = (fi >= 256) ? bscan[(fi >> 8) - 1] : 0;
        cur[b] = histincl[fi] + boff - hist[fi];
    }
    __syncthreads();
    int e0 = blk * CH;
    int e1 = min(e0 + CH, E);
    int i64 = flag[0];
    for (int e = e0 + threadIdx.x; e < e1; e += 256) {
        int s, d;
        if (i64) {
            const long long* e64 = (const long long*)ei;
            s = (int)e64[e]; d = (int)e64[(size_t)E + e];
        } else {
            s = ei[e]; d = ei[(size_t)E + e];
        }
        int b = ((unsigned)d < (unsigned)n) ? min(d >> shiftv, NBUK - 1) : (NBUK - 1);
        int pos = atomicAdd(&cur[b], 1);
        ebuf[pos] = ((long long)(unsigned)d << 32) | (unsigned)s;
    }
}

// per-bucket degree count on SORTED ebuf: LDS counters, no global atomics.
// bucket b's slice is contiguous: [start(b), start(b+1)); window = 1<<shiftv nodes.
// NOTE: reads the EDGE-HIST scan (histincl/bscan/hist) — must run before any
// other kernel reuses those scan buffers [r6 bug: bscan was clobbered].
__global__ void countS_k(const long long* __restrict__ ebuf,
                         const int* __restrict__ histincl, const int* __restrict__ bscan,
                         const int* __restrict__ hist, int* __restrict__ counts,
                         int E, int n, int NB, int NBUK, int shiftv) {
    __shared__ int cnt[256];
    __shared__ int sse[2];
    int b = blockIdx.x;
    int t = threadIdx.x;
    if (t < 2) {
        int bb = b + t;
        int v;
        if (bb >= NBUK) v = E;
        else {
            int fi = bb * NB;
            int boff = (fi >= 256) ? bscan[(fi >> 8) - 1] : 0;
            v = histincl[fi] + boff - hist[fi];
        }
        sse[t] = v;
    }
    __syncthreads();
    int sb = sse[0], se = sse[1];
    int base = b << shiftv;
    int W = 1 << shiftv;
    for (int w0 = 0; w0 < W; w0 += 256) {     // 1 pass when shiftv==8 (N=50000)
        cnt[t] = 0;
        __syncthreads();
        for (int e = sb + t; e < se; e += 256) {
            int d = (int)(ebuf[e] >> 32);
            int loc = d - base - w0;
            if ((unsigned)d < (unsigned)n && (unsigned)loc < 256u)
                atomicAdd(&cnt[loc], 1);
        }
        __syncthreads();
        int i = base + w0 + t;
        if (i < n) counts[i] = cnt[t] + 1;    // +1 self-loop
        __syncthreads();
    }
}

// fused CSR epilogue: rowptr + dinv (reads NODE-degree scan nincl/nbscan)
__global__ void finCSR_k(const int* __restrict__ nincl, const int* __restrict__ nbscan,
                         const int* __restrict__ counts, int* __restrict__ rowptr,
                         float* __restrict__ dinv, int n) {
    int i = blockIdx.x * SCAN_B + threadIdx.x;
    if (i < n) {
        int boff = (blockIdx.x > 0) ? nbscan[blockIdx.x - 1] : 0;
        int rp_end = nincl[i] + boff;        // inclusive scan = row end
        rowptr[i + 1] = rp_end;
        if (i == 0) rowptr[0] = 0;
        dinv[i] = rsqrtf((float)counts[i]);
    }
}

// per-bucket CSR scatter from SORTED ebuf: LDS cursor table, no global atomics.
// Reads the EDGE-HIST scan (histincl/bscan/hist) for slice bounds — those
// buffers are preserved (node scan uses nbsum/nbscan) [r6 fix].
__global__ void scatDS_k(const long long* __restrict__ ebuf,
                         const int* __restrict__ histincl, const int* __restrict__ bscan,
                         const int* __restrict__ hist, const int* __restrict__ rowptr,
                         int* __restrict__ col,
                         int E, int n, int NB, int NBUK, int shiftv) {
    __shared__ int cur[256];
    __shared__ int sse[2];
    int b = blockIdx.x;
    int t = threadIdx.x;
    if (t < 2) {
        int bb = b + t;
        int v;
        if (bb >= NBUK) v = E;
        else {
            int fi = bb * NB;
            int boff = (fi >= 256) ? bscan[(fi >> 8) - 1] : 0;
            v = histincl[fi] + boff - hist[fi];
        }
        sse[t] = v;
    }
    __syncthreads();
    int sb = sse[0], se = sse[1];
    int base = b << shiftv;
    int W = 1 << shiftv;
    for (int w0 = 0; w0 < W; w0 += 256) {     // 1 pass when shiftv==8
        int node = base + w0 + t;
        cur[t] = (node < n) ? rowptr[node] : 0;
        __syncthreads();
        for (int e = sb + t; e < se; e += 256) {
            long long pr = ebuf[e];
            int d = (int)(pr >> 32);
            int s = (int)(pr & 0xffffffffLL);
            int loc = d - base - w0;
            if ((unsigned)d < (unsigned)n && (unsigned)s < (unsigned)n &&
                (unsigned)loc < 256u) {
                int pos = atomicAdd(&cur[loc], 1);   // LDS atomic
                col[pos] = s;
            }
        }
        __syncthreads();
        if (node < n) col[cur[t]] = node;     // self-loop append, no atomic
        __syncthreads();
    }
}

// ---------------- bf16 MFMA GEMM, 2-phase double-buffered ----------------------------
typedef __attribute__((address_space(1))) const void gas_v;
typedef __attribute__((address_space(3))) void las_v;

__global__ __launch_bounds__(256) void gemm128_k(
    const u16* __restrict__ A, const u16* __restrict__ Bt,
    u16* __restrict__ C, int M, int K, int Nn, int nyv) {
    int nx = (M + 127) >> 7;
    int nfull = nx & ~7;
    int cutoff = nfull * nyv;
    int b = blockIdx.x;
    int bx, by;
    if (b < cutoff) {
        int k = b & 7;            // XCD id (blockIdx % 8 round-robin [m09])
        int q = b >> 3;
        by = q % nyv;
        bx = (q / nyv) * 8 + k;   // all ny blocks of panel bx share XCD k
    } else {
        int r = b - cutoff;
        bx = nfull + r / nyv;
        by = r % nyv;
    }

    __shared__ u16 As[2][128 * 32];
    __shared__ u16 Bs[2][128 * 32];
    int tid = threadIdx.x;
    int wave = tid >> 6;
    int lane = tid & 63;
    int wr = (wave >> 1) * 64;   // wave row offset in tile
    int wc = (wave & 1) * 64;    // wave col offset in tile
    long row0 = (long)bx * 128;
    int col0 = by * 128;
    int lr = lane >> 2;          // 0..15 : row within 16-row staging chunk
    int lc = lane & 3;           // 0..3  : 16B column chunk
    int m = lane & 15;
    int q = lane >> 4;

    long ar0 = row0 + (wave + 0) * 16 + lr;
    long ar1 = row0 + (wave + 4) * 16 + lr;
    if (ar0 > (long)M - 1) ar0 = (long)M - 1;  // clamp: garbage feeds masked rows only
    if (ar1 > (long)M - 1) ar1 = (long)M - 1;
    const u16* gA0 = A + ar0 * K + lc * 8;
    const u16* gA1 = A + ar1 * K + lc * 8;
    const u16* gB0 = Bt + (size_t)(col0 + (wave + 0) * 16 + lr) * K + lc * 8;
    const u16* gB1 = Bt + (size_t)(col0 + (wave + 4) * 16 + lr) * K + lc * 8;
    int lds0 = (wave + 0) * 512;
    int lds1 = (wave + 4) * 512;

    f32x4 acc[4][4];
    #pragma unroll
    for (int i = 0; i < 4; i++)
        #pragma unroll
        for (int j = 0; j < 4; j++) acc[i][j] = (f32x4){0.f, 0.f, 0.f, 0.f};

    __builtin_amdgcn_global_load_lds((gas_v*)(gA0), (las_v*)&As[0][lds0], 16, 0, 0);
    __builtin_amdgcn_global_load_lds((gas_v*)(gA1), (las_v*)&As[0][lds1], 16, 0, 0);
    __builtin_amdgcn_global_load_lds((gas_v*)(gB0), (las_v*)&Bs[0][lds0], 16, 0, 0);
    __builtin_amdgcn_global_load_lds((gas_v*)(gB1), (las_v*)&Bs[0][lds1], 16, 0, 0);
    __syncthreads();

    int cur = 0;
    for (int k0 = 0; k0 < K; k0 += 32) {
        if (k0 + 32 < K) {
            int nb = cur ^ 1;
            int ko = k0 + 32;
            __builtin_amdgcn_global_load_lds((gas_v*)(gA0 + ko), (las_v*)&As[nb][lds0], 16, 0, 0);
            __builtin_amdgcn_global_load_lds((gas_v*)(gA1 + ko), (las_v*)&As[nb][lds1], 16, 0, 0);
            __builtin_amdgcn_global_load_lds((gas_v*)(gB0 + ko), (las_v*)&Bs[nb][lds0], 16, 0, 0);
            __builtin_amdgcn_global_load_lds((gas_v*)(gB1 + ko), (las_v*)&Bs[nb][lds1], 16, 0, 0);
        }

        us8 av[4], bv[4];
        #pragma unroll
        for (int i = 0; i < 4; i++) {
            av[i] = *(const us8*)&As[cur][(wr + i * 16 + m) * 32 + q * 8];
            bv[i] = *(const us8*)&Bs[cur][(wc + i * 16 + m) * 32 + q * 8];
        }
        #pragma unroll
        for (int i = 0; i < 4; i++) {
            bf8 fa = __builtin_bit_cast(bf8, av[i]);
            #pragma unroll
            for (int j = 0; j < 4; j++) {
                bf8 fb = __builtin_bit_cast(bf8, bv[j]);
                acc[i][j] = __builtin_amdgcn_mfma_f32_16x16x32_bf16(fa, fb, acc[i][j], 0, 0, 0);
            }
        }
        __syncthreads();
        cur ^= 1;
    }

    // C/D layout: col = lane&15, row = (lane>>4)*4 + r  [measured m89]
    #pragma unroll
    for (int i = 0; i < 4; i++) {
        #pragma unroll
        for (int r = 0; r < 4; r++) {
            long row = row0 + wr + i * 16 + q * 4 + r;
            if (row < M) {
                #pragma unroll
                for (int j = 0; j < 4; j++)
                    C[row * Nn + col0 + wc + j * 16 + m] = f2bf(acc[i][j][r]);
            }
        }
    }
}

// ---------------- wave-per-node aggregate [+ bias + LN + ELU (+resid) (+classifier)] ---
template <int F>
__global__ __launch_bounds__(256) void agg_k(
    const u16* __restrict__ in, const int* __restrict__ rowptr,
    const int* __restrict__ col, const float* __restrict__ dinv,
    const float* __restrict__ bias, const float* __restrict__ gamma,
    const float* __restrict__ beta, u16* __restrict__ out_h,
    const u16* __restrict__ resid, void* __restrict__ final_base,
    const int* __restrict__ flag, const float* __restrict__ Wcf,
    const float* __restrict__ bcf, int nN) {
    int wv = threadIdx.x >> 6;
    int lane = threadIdx.x & 63;
    int i = blockIdx.x * 4 + wv;
    if (i >= nN) return;

    constexpr int rowt = F >> 3;          // 32 (F=256) or 16 (F=128)
    constexpr int Gw = 64 / rowt;         // 2 or 4 edge groups per wave
    int g = lane / rowt;
    int f0 = (lane & (rowt - 1)) << 3;

    int beg = rowptr[i], end = rowptr[i + 1];
    f32x8 acc = {0, 0, 0, 0, 0, 0, 0, 0}, acc2 = acc;
    int e = beg + g;
    for (; e + Gw < end; e += 2 * Gw) {
        int s0 = col[e], s1 = col[e + Gw];
        s0 = ((unsigned)s0 < (unsigned)nN) ? s0 : 0;
        s1 = ((unsigned)s1 < (unsigned)nN) ? s1 : 0;
        float w0 = dinv[s0], w1 = dinv[s1];
        us8 v0 = *(const us8*)(in + (unsigned)(s0 * F) + f0);
        us8 v1 = *(const us8*)(in + (unsigned)(s1 * F) + f0);
        fma8(acc, w0, v0);
        fma8(acc2, w1, v1);
    }
    if (e < end) {
        int s = col[e];
        s = ((unsigned)s < (unsigned)nN) ? s : 0;
        us8 v = *(const us8*)(in + (unsigned)(s * F) + f0);
        fma8(acc, dinv[s], v);
    }
    #pragma unroll
    for (int j = 0; j < 8; j++) acc[j] += acc2[j];

    #pragma unroll
    for (int o = 32; o >= rowt; o >>= 1) {
        #pragma unroll
        for (int j = 0; j < 8; j++) acc[j] += __shfl_down(acc[j], o);
    }
    bool active = lane < rowt;
    float di = dinv[i];

    if (!bias) {  // plain mode (layer-2 pre-aggregate)
        if (active) {
            us8 o8;
            #pragma unroll
            for (int j = 0; j < 8; j++) o8[j] = f2bf(di * acc[j]);
            *(us8*)(out_h + (unsigned)(i * F) + f0) = o8;
        }
        return;
    }

    f32x8 accv = {0, 0, 0, 0, 0, 0, 0, 0};
    if (active) {
        #pragma unroll
        for (int j = 0; j < 8; j++) accv[j] = di * acc[j] + bias[f0 + j];
    }
    int f32m = final_base ? flag[1] : 0;
    if (final_base && active) {
        size_t conv_idx = (size_t)nN * 4 + (size_t)i * F + f0;
        if (f32m) {
            #pragma unroll
            for (int j = 0; j < 8; j++) ((float*)final_base)[conv_idx + j] = accv[j];
        } else {
            us8 o8;
            #pragma unroll
            for (int j = 0; j < 8; j++) o8[j] = f2bf(accv[j]);
            *(us8*)((u16*)final_base + conv_idx) = o8;
        }
    }

    float p1 = 0.f, p2 = 0.f;
    #pragma unroll
    for (int j = 0; j < 8; j++) { p1 += accv[j]; p2 += accv[j] * accv[j]; }
    #pragma unroll
    for (int o = rowt >> 1; o >= 1; o >>= 1) {
        p1 += __shfl_xor(p1, o);
        p2 += __shfl_xor(p2, o);
    }
    constexpr float invF = 1.0f / (float)F;
    float mu = p1 * invF;
    float var = fmaxf(p2 * invF - mu * mu, 0.f);
    float rstd = rsqrtf(var + 1e-5f);

    f32x8 h8 = {0, 0, 0, 0, 0, 0, 0, 0};
    if (active) {
        f32x8 y8;
        #pragma unroll
        for (int j = 0; j < 8; j++)
            y8[j] = (accv[j] - mu) * rstd * gamma[f0 + j] + beta[f0 + j];
        if (final_base) {
            size_t bn_idx = (size_t)nN * 4 + (size_t)nN * F + (size_t)i * F + f0;
            if (f32m) {
                #pragma unroll
                for (int j = 0; j < 8; j++) ((float*)final_base)[bn_idx + j] = y8[j];
            } else {
                us8 o8;
                #pragma unroll
                for (int j = 0; j < 8; j++) o8[j] = f2bf(y8[j]);
                *(us8*)((u16*)final_base + bn_idx) = o8;
            }
        }
        #pragma unroll
        for (int j = 0; j < 8; j++) h8[j] = (y8[j] > 0.f) ? y8[j] : expm1f(y8[j]);
        if (resid) {
            us8 r8 = *(const us8*)(resid + (unsigned)(i * F) + f0);
            #pragma unroll
            for (int j = 0; j < 8; j++) h8[j] += bf2f(r8[j]);
        }
        if (out_h) {
            us8 o8;
            #pragma unroll
            for (int j = 0; j < 8; j++) o8[j] = f2bf(h8[j]);
            *(us8*)(out_h + (unsigned)(i * F) + f0) = o8;
        }
    }

    if (Wcf) {
        float s0 = 0.f, s1 = 0.f, s2 = 0.f, s3 = 0.f;
        if (active) {
            #pragma unroll
            for (int j = 0; j < 8; j++) {
                const float* wr = Wcf + (f0 + j) * 4;
                s0 += h8[j] * wr[0];
                s1 += h8[j] * wr[1];
                s2 += h8[j] * wr[2];
                s3 += h8[j] * wr[3];
            }
        }
        #pragma unroll
        for (int o = rowt >> 1; o >= 1; o >>= 1) {
            s0 += __shfl_xor(s0, o);
            s1 += __shfl_xor(s1, o);
            s2 += __shfl_xor(s2, o);
            s3 += __shfl_xor(s3, o);
        }
        if (lane == 0) {
            size_t lidx = (size_t)i * 4;
            if (f32m) {
                ((float*)final_base)[lidx + 0] = s0 + bcf[0];
                ((float*)final_base)[lidx + 1] = s1 + bcf[1];
                ((float*)final_base)[lidx + 2] = s2 + bcf[2];
                ((float*)final_base)[lidx + 3] = s3 + bcf[3];
            } else {
                ((u16*)final_base)[lidx + 0] = f2bf(s0 + bcf[0]);
                ((u16*)final_base)[lidx + 1] = f2bf(s1 + bcf[1]);
                ((u16*)final_base)[lidx + 2] = f2bf(s2 + bcf[2]);
                ((u16*)final_base)[lidx + 3] = f2bf(s3 + bcf[3]);
            }
        }
    }
}

// ---------------- bias + LayerNorm + ELU in place, wave-per-node, F=512 ----------
__global__ __launch_bounds__(256) void ln_elu_k(u16* __restrict__ h,
                                                const float* __restrict__ bias,
                                                const float* __restrict__ gamma,
                                                const float* __restrict__ beta, int nN) {
    int wv = threadIdx.x >> 6;
    int lane = threadIdx.x & 63;
    int i = blockIdx.x * 4 + wv;
    if (i >= nN) return;
    int f0 = lane * 8;                       // 64 lanes x 8 = 512 features
    size_t base = (size_t)i * 512 + f0;
    us8 v8 = *(const us8*)(h + base);
    f32x8 v;
    #pragma unroll
    for (int j = 0; j < 8; j++) v[j] = bf2f(v8[j]) + bias[f0 + j];
    float p1 = 0.f, p2 = 0.f;
    #pragma unroll
    for (int j = 0; j < 8; j++) { p1 += v[j]; p2 += v[j] * v[j]; }
    #pragma unroll
    for (int o = 32; o >= 1; o >>= 1) {
        p1 += __shfl_xor(p1, o);
        p2 += __shfl_xor(p2, o);
    }
    const float invF = 1.0f / 512.0f;
    float mu = p1 * invF;
    float var = fmaxf(p2 * invF - mu * mu, 0.f);
    float rstd = rsqrtf(var + 1e-5f);
    us8 o8;
    #pragma unroll
    for (int j = 0; j < 8; j++) {
        float y = (v[j] - mu) * rstd * gamma[f0 + j] + beta[f0 + j];
        y = (y > 0.f) ? y : expm1f(y);
        o8[j] = f2bf(y);
    }
    *(us8*)(h + base) = o8;
}

// ---------------- ws-too-small marker ----------------
__global__ void marker_k(float* out) {
    if (threadIdx.x == 0 && blockIdx.x == 0) {
        out[0] = 31337.0f; out[1] = 31337.0f;
    }
}

extern "C" void kernel_launch(void* const* d_in, const int* in_sizes, int n_in,
                              void* d_out, int out_size, void* d_ws, size_t ws_size,
                              hipStream_t stream) {
    const int N = in_sizes[0] / 512;   // 50000
    const int E = in_sizes[1] / 2;     // 1600000

    const void* x  = d_in[0];
    const int* ei  = (const int*)d_in[1];

    // ---- workspace carve ----
    char* p = (char*)d_ws;
    auto alloc = [&](size_t bytes) -> void* {
        void* r = (void*)p;
        p += (bytes + 255) & ~(size_t)255;
        return r;
    };
    int*   flag   = (int*)alloc(256);
    int*   counts = (int*)alloc((size_t)N * 4);
    int*   rowptr = (int*)alloc((size_t)(N + 1) * 4);
    int*   incl   = (int*)alloc((size_t)N * 4);
    int*   bsum   = (int*)alloc(256 * 4);   // edge-hist scan partials
    int*   bscan  = (int*)alloc(256 * 4);   // edge-hist scan (used by scatC/countS/scatDS)
    int*   nbsum  = (int*)alloc(256 * 4);   // node-degree scan partials [r6 fix]
    int*   nbscan = (int*)alloc(256 * 4);   // node-degree scan (used by finCSR only)
    float* dinv   = (float*)alloc((size_t)N * 4);
    int*   col    = (int*)alloc((size_t)(E + N) * 4);
    float* pbuf   = (float*)alloc(4096 * 4);
    u16* W1t = (u16*)alloc((size_t)512 * 256 * 2);
    u16* W2t = (u16*)alloc((size_t)256 * 512 * 2);
    u16* W3t = (u16*)alloc((size_t)512 * 256 * 2);
    u16* W4t = (u16*)alloc((size_t)256 * 128 * 2);
    u16* bigA = (u16*)alloc((size_t)N * 512 * 2);  // xbf -> h2
    u16* xw   = (u16*)alloc((size_t)N * 256 * 2);  // ebuf (CSR build) -> GEMM scratch
    u16* h1   = (u16*)alloc((size_t)N * 256 * 2);  // hist arrays (CSR build) -> h1

    size_t needed = (size_t)(p - (char*)d_ws);
    if (needed > ws_size) {
        marker_k<<<1, 64, 0, stream>>>((float*)d_out);
        return;
    }

    u16* xbf = bigA;
    u16* h2  = bigA;  // [N,512], alive after xbf dead

    int shiftv = 8;
    while (((N - 1) >> shiftv) > 255) shiftv++;
    int NBUK = ((N - 1) >> shiftv) + 1;            // 196 for N=50000
    int NB_E = (E + CH - 1) / CH;                  // 196 for E=1.6M
    int flatlen = NBUK * NB_E;                     // ~38k
    int NH = (flatlen + 255) / 256;                // <=256 required
    long long* ebuf = (long long*)xw;              // E*8 B <= N*256*2 B
    int* hist     = (int*)h1;
    int* histincl = hist + flatlen;

    PTab tab;
    tab.e[0]  = { d_in[3],  256, 0    };  // b1
    tab.e[1]  = { d_in[12], 256, 256  };  // g1
    tab.e[2]  = { d_in[13], 256, 512  };  // be1
    tab.e[3]  = { d_in[5],  512, 768  };  // b2
    tab.e[4]  = { d_in[14], 512, 1280 };  // g2
    tab.e[5]  = { d_in[15], 512, 1792 };  // be2
    tab.e[6]  = { d_in[7],  256, 2304 };  // b3
    tab.e[7]  = { d_in[16], 256, 2560 };  // g3
    tab.e[8]  = { d_in[17], 256, 2816 };  // be3
    tab.e[9]  = { d_in[9],  128, 3072 };  // b4
    tab.e[10] = { d_in[18], 128, 3200 };  // g4
    tab.e[11] = { d_in[19], 128, 3328 };  // be4
    tab.e[12] = { d_in[10], 512, 3456 };  // Wc
    tab.e[13] = { d_in[11], 4,   3968 };  // bc
    float* b1f = pbuf + 0,   *g1f = pbuf + 256,  *be1f = pbuf + 512;
    float* b2f = pbuf + 768, *g2f = pbuf + 1280, *be2f = pbuf + 1792;
    float* b3f = pbuf + 2304,*g3f = pbuf + 2560, *be3f = pbuf + 2816;
    float* b4f = pbuf + 3072,*g4f = pbuf + 3200, *be4f = pbuf + 3328;
    float* Wcf = pbuf + 3456,*bcf = pbuf + 3968;

    int NB = (N + SCAN_B - 1) / SCAN_B;

    // ---- dtype probes ----
    detect_k<<<1, 256, 0, stream>>>(ei, E, (const u16*)x, flag);

    // ---- canonicalize (x + weights + params, one kernel) ----
    {
        WEnt e0 = { d_in[2], W1t, 512, 256, 0 };
        WEnt e1 = { d_in[4], W2t, 256, 512, 512 * 256 };
        WEnt e2 = { d_in[6], W3t, 512, 256, 512 * 256 + 256 * 512 };
        WEnt e3 = { d_in[8], W4t, 256, 128, 512 * 256 * 2 + 256 * 512 };
        int wtotal = 512 * 256 * 2 + 256 * 512 + 256 * 128;
        int gw = (wtotal + 255) / 256;
        megacvt_k<<<GX_CVT + gw + 14, 256, 0, stream>>>(
            x, xbf, (long)N * 512 / 4, e0, e1, e2, e3, wtotal, tab, pbuf, flag, gw);
    }

    // ---- CSR build (bucket-sorted, zero global atomics) ----
    histA_k<<<NB_E, 256, 0, stream>>>(ei, flag, hist, E, N, NB_E, NBUK, shiftv);
    scan1_k<<<NH, SCAN_B, 0, stream>>>(hist, histincl, bsum, flatlen);
    scan2_k<<<1, SCAN_B, 0, stream>>>(bsum, bscan, NH);
    scatC_k<<<NB_E, 256, 0, stream>>>(ei, flag, histincl, bscan, hist, ebuf,
                                      E, N, NB_E, NBUK, shiftv);
    countS_k<<<NBUK, 256, 0, stream>>>(ebuf, histincl, bscan, hist, counts,
                                       E, N, NB_E, NBUK, shiftv);
    scan1_k<<<NB, SCAN_B, 0, stream>>>(counts, incl, nbsum, N);
    scan2_k<<<1, SCAN_B, 0, stream>>>(nbsum, nbscan, NB);
    finCSR_k<<<NB, SCAN_B, 0, stream>>>(incl, nbscan, counts, rowptr, dinv, N);
    scatDS_k<<<NBUK, 256, 0, stream>>>(ebuf, histincl, bscan, hist, rowptr, col,
                                       E, N, NB_E, NBUK, shiftv);

    int gx = (N + 127) / 128;          // 391
    int ga = (N + 3) / 4;

    // ---- layer 1: xbf[N,512] @ W1 -> agg+LN+ELU -> h1[N,256] ----
    gemm128_k<<<gx * 2, 256, 0, stream>>>(xbf, W1t, xw, N, 512, 256, 2);
    agg_k<256><<<ga, 256, 0, stream>>>(xw, rowptr, col, dinv, b1f, g1f, be1f,
                                       h1, nullptr, nullptr, flag, nullptr, nullptr, N);
    // ---- layer 2 (agg BEFORE GEMM: agg(h1 @ W2) == agg(h1) @ W2) ----
    agg_k<256><<<ga, 256, 0, stream>>>(h1, rowptr, col, dinv, nullptr, nullptr, nullptr,
                                       xw, nullptr, nullptr, flag, nullptr, nullptr, N);
    gemm128_k<<<gx * 4, 256, 0, stream>>>(xw, W2t, h2, N, 256, 512, 4);
    ln_elu_k<<<ga, 256, 0, stream>>>(h2, b2f, g2f, be2f, N);
    // ---- layer 3: h2[N,512] @ W3 -> agg+LN+ELU + h1 -> h1[N,256] ----
    gemm128_k<<<gx * 2, 256, 0, stream>>>(h2, W3t, xw, N, 512, 256, 2);
    agg_k<256><<<ga, 256, 0, stream>>>(xw, rowptr, col, dinv, b3f, g3f, be3f,
                                       h1, h1, nullptr, flag, nullptr, nullptr, N);
    // ---- layer 4: h1[N,256] @ W4 -> agg -> out_conv/out_bn + fused classifier ----
    gemm128_k<<<gx * 1, 256, 0, stream>>>(h1, W4t, xw, N, 256, 128, 1);
    agg_k<128><<<ga, 256, 0, stream>>>(xw, rowptr, col, dinv, b4f, g4f, be4f,
                                       nullptr, nullptr, d_out, flag, Wcf, bcf, N);
}